// Round 13
// baseline (1747.116 us; speedup 1.0000x reference)
//
#include <hip/hip_runtime.h>
#include <math.h>

#define B_    64
#define T_    256
#define N_    61
#define FIN_  3
#define GH_   64
#define LH_   128
#define NC_   10
#define NG_   3904      /* N_*GH_ */
#define M_TOT 16384     /* B_*T_  */
#define CHUNK_M 8192
#define SUB_M   2048    /* GCN sub-chunk */

typedef __attribute__((ext_vector_type(8))) short bf16x8;
typedef __attribute__((ext_vector_type(4))) float f32x4;

__device__ __forceinline__ float gelu_exact(float x) {
    return 0.5f * x * (1.0f + erff(x * 0.70710678118654752f));
}
__device__ __forceinline__ float sigmoidf_(float x) {
    return 1.0f / (1.0f + expf(-x));
}
__device__ __forceinline__ unsigned short f2bf(float f) {
    unsigned int u = __float_as_uint(f);
    u = (u + 0x7FFFu + ((u >> 16) & 1u)) >> 16;
    return (unsigned short)u;
}
__device__ __forceinline__ void store_h(float* p, float v) { *p = v; }
__device__ __forceinline__ void store_h(unsigned short* p, float v) { *p = f2bf(v); }

__device__ __forceinline__ void gload_lds16(const void* g, void* l) {
    __builtin_amdgcn_global_load_lds(
        (const __attribute__((address_space(1))) unsigned int*)g,
        (__attribute__((address_space(3))) unsigned int*)l,
        16, 0, 0);
}

// Shared 64-elem-row swizzle: XOR k with (row&3)*16. Used identically by every
// writer (global pre-swizzle) and reader (LDS frag read) — both-sides-or-neither.
__device__ __forceinline__ int swz(int row, int k) { return k ^ ((row & 3) << 4); }

// byte-level row swizzle for 256B bf16 rows (T2): same map on write and read.
__device__ __forceinline__ int hswz(int row, int byteoff) { return byteoff ^ ((row & 7) << 4); }

// ---------------------------------------------------------------------------
// fp32 -> bf16 weight conversion (4 elems/thread). n4 = ELEMENT count / 4.
// ---------------------------------------------------------------------------
__global__ __launch_bounds__(256) void cvt_bf16_kernel(
    const float* __restrict__ in, unsigned short* __restrict__ out, int n4)
{
    int i = blockIdx.x * 256 + threadIdx.x;
    if (i < n4) {
        float4 v = reinterpret_cast<const float4*>(in)[i];
        ushort4 o;
        o.x = f2bf(v.x); o.y = f2bf(v.y); o.z = f2bf(v.z); o.w = f2bf(v.w);
        reinterpret_cast<ushort4*>(out)[i] = o;
    }
}

// adj (61x61 fp32) -> adjb (64x64 bf16, zero-padded, pre-swizzled). grid 16.
__global__ __launch_bounds__(256) void cvt_adj_kernel(
    const float* __restrict__ adj, unsigned short* __restrict__ adjb)
{
    int i = blockIdx.x * 256 + threadIdx.x;
    if (i < 4096) {
        int n = i >> 6, m = i & 63;
        unsigned short v = (n < N_ && m < N_) ? f2bf(adj[n * N_ + m]) : (unsigned short)0;
        adjb[n * 64 + swz(n, m)] = v;
    }
}

// W2 (64x64 fp32) -> w2b (64x64 bf16, pre-swizzled). grid 16.
__global__ __launch_bounds__(256) void cvt_w2_kernel(
    const float* __restrict__ W2, unsigned short* __restrict__ w2b)
{
    int i = blockIdx.x * 256 + threadIdx.x;
    if (i < 4096) {
        int c = i >> 6, f = i & 63;
        w2b[c * 64 + swz(c, f)] = f2bf(W2[c * 64 + f]);
    }
}

// ---------------------------------------------------------------------------
// GCN K1: per (b,t): AX = A@X (fp32), H1 = gelu(AX @ W1^T + b1).
// Writes H1W bf16 TRANSPOSED [btl*64+c][m], m=61..63 zeroed, pre-swizzled.
// ---------------------------------------------------------------------------
__global__ __launch_bounds__(256) void gcn_h1_kernel(
    const float* __restrict__ x, const float* __restrict__ adj,
    const float* __restrict__ W1, const float* __restrict__ b1,
    unsigned short* __restrict__ H1W, int bt_base)
{
    __shared__ float adjs[N_ * 65];
    __shared__ float h1s [N_ * 65];
    __shared__ float xs [184];
    __shared__ float axs[184];
    __shared__ float w1s[192];
    __shared__ float b1s[64];

    const int tid = threadIdx.x;
    const int bt  = bt_base + blockIdx.x;

    for (int i = tid; i < N_ * N_; i += 256) {
        int n = i / 61, m = i - n * 61;
        adjs[n * 65 + m] = adj[i];
    }
    for (int i = tid; i < N_ * FIN_; i += 256) xs[i] = x[(size_t)bt * (N_ * FIN_) + i];
    for (int i = tid; i < GH_ * FIN_; i += 256) w1s[i] = W1[i];
    if (tid < GH_) b1s[tid] = b1[tid];
    __syncthreads();

    if (tid < N_ * FIN_) {
        int n = tid / 3, f = tid - n * 3;
        float acc = 0.f;
        for (int m = 0; m < N_; ++m) acc += adjs[n * 65 + m] * xs[m * 3 + f];
        axs[tid] = acc;
    }
    __syncthreads();

    for (int u = 0; u < 16; ++u) {
        int idx = tid + u * 256;
        if (idx < N_ * GH_) {
            int m = idx >> 6, c = idx & 63;
            float acc = b1s[c];
            acc += axs[m * 3 + 0] * w1s[c * 3 + 0];
            acc += axs[m * 3 + 1] * w1s[c * 3 + 1];
            acc += axs[m * 3 + 2] * w1s[c * 3 + 2];
            h1s[m * 65 + c] = gelu_exact(acc);
        }
    }
    __syncthreads();

    unsigned short* dst = H1W + (size_t)blockIdx.x * 4096;
    for (int i = tid; i < 4096; i += 256) {
        int c = i >> 6, m = i & 63;
        unsigned short v = (m < N_) ? f2bf(h1s[m * 65 + c]) : (unsigned short)0;
        dst[c * 64 + swz(c, m)] = v;
    }
}

// ---------------------------------------------------------------------------
// GCN K23: per block = 2 consecutive bt. MFMA both heavy stages.
// ---------------------------------------------------------------------------
__global__ __launch_bounds__(256) void gcn_mix_kernel(
    const unsigned short* __restrict__ H1W,
    const unsigned short* __restrict__ adjb,
    const unsigned short* __restrict__ w2b,
    const float* __restrict__ b2,
    unsigned short* __restrict__ seqc,
    int sc_base)
{
    __shared__ unsigned short adjbs[64 * 64];
    __shared__ unsigned short b1t [128 * 64];
    __shared__ unsigned short w2bs[64 * 64];
    __shared__ unsigned short T   [128 * 64];
    __shared__ float b2s[64];

    const int tid = threadIdx.x;
    const int w   = tid >> 6;
    const int l   = tid & 63;
    const int lr  = l & 15, lk = l >> 4;
    const int p   = blockIdx.x;

    #pragma unroll
    for (int q = 0; q < 2; ++q)
        gload_lds16(adjb + q * 2048 + w * 512 + l * 8, &adjbs[q * 2048 + w * 512]);
    #pragma unroll
    for (int q = 0; q < 2; ++q)
        gload_lds16(w2b + q * 2048 + w * 512 + l * 8, &w2bs[q * 2048 + w * 512]);
    #pragma unroll
    for (int q = 0; q < 4; ++q)
        gload_lds16(H1W + (size_t)p * 8192 + q * 2048 + w * 512 + l * 8,
                    &b1t[q * 2048 + w * 512]);
    if (tid < 64) b2s[tid] = b2[tid];
    __syncthreads();

    f32x4 acc1[4][2];
    #pragma unroll
    for (int i = 0; i < 4; ++i)
        #pragma unroll
        for (int j = 0; j < 2; ++j) acc1[i][j] = (f32x4){0.f, 0.f, 0.f, 0.f};

    #pragma unroll
    for (int kk = 0; kk < 2; ++kk) {
        const int kb = kk * 32 + lk * 8;
        bf16x8 af[4], bfr[2];
        #pragma unroll
        for (int i = 0; i < 4; ++i) {
            int rn = i * 16 + lr;
            af[i] = *reinterpret_cast<const bf16x8*>(&adjbs[rn * 64 + swz(rn, kb)]);
        }
        #pragma unroll
        for (int j = 0; j < 2; ++j) {
            int rb = w * 32 + j * 16 + lr;
            bfr[j] = *reinterpret_cast<const bf16x8*>(&b1t[rb * 64 + swz(rb, kb)]);
        }
        #pragma unroll
        for (int i = 0; i < 4; ++i)
            #pragma unroll
            for (int j = 0; j < 2; ++j)
                acc1[i][j] = __builtin_amdgcn_mfma_f32_16x16x32_bf16(af[i], bfr[j], acc1[i][j], 0, 0, 0);
    }

    #pragma unroll
    for (int i = 0; i < 4; ++i) {
        #pragma unroll
        for (int j = 0; j < 2; ++j) {
            int col = w * 32 + j * 16 + lr;
            int c   = col & 63;
            int rbase = (col >> 6) * 64;
            #pragma unroll
            for (int r = 0; r < 4; ++r) {
                int n   = i * 16 + lk * 4 + r;
                int row = rbase + n;
                T[row * 64 + swz(row, c)] = f2bf(acc1[i][j][r]);
            }
        }
    }
    __syncthreads();

    f32x4 acc2[2][4];
    #pragma unroll
    for (int i = 0; i < 2; ++i)
        #pragma unroll
        for (int j = 0; j < 4; ++j) acc2[i][j] = (f32x4){0.f, 0.f, 0.f, 0.f};

    #pragma unroll
    for (int kk = 0; kk < 2; ++kk) {
        const int kb = kk * 32 + lk * 8;
        bf16x8 a2[2], bw[4];
        #pragma unroll
        for (int i = 0; i < 2; ++i) {
            int r2 = w * 32 + i * 16 + lr;
            a2[i] = *reinterpret_cast<const bf16x8*>(&T[r2 * 64 + swz(r2, kb)]);
        }
        #pragma unroll
        for (int j = 0; j < 4; ++j) {
            int co = j * 16 + lr;
            bw[j] = *reinterpret_cast<const bf16x8*>(&w2bs[co * 64 + swz(co, kb)]);
        }
        #pragma unroll
        for (int i = 0; i < 2; ++i)
            #pragma unroll
            for (int j = 0; j < 4; ++j)
                acc2[i][j] = __builtin_amdgcn_mfma_f32_16x16x32_bf16(a2[i], bw[j], acc2[i][j], 0, 0, 0);
    }

    #pragma unroll
    for (int i = 0; i < 2; ++i) {
        #pragma unroll
        for (int j = 0; j < 4; ++j) {
            int co = j * 16 + lr;
            float bias = b2s[co];
            #pragma unroll
            for (int r = 0; r < 4; ++r) {
                int row = w * 32 + i * 16 + lk * 4 + r;
                int n   = row & 63;
                if (n < N_) {
                    int btc = sc_base + p * 2 + (row >> 6);
                    seqc[(size_t)btc * NG_ + n * 64 + co] =
                        f2bf(gelu_exact(acc2[i][j][r] + bias));
                }
            }
        }
    }
}

// ---------------------------------------------------------------------------
// bf16 MFMA GEMM: C = A(Mc x K) @ W(1024 x K)^T + bias_a + bias_b
// ---------------------------------------------------------------------------
__global__ __launch_bounds__(256) void gemm_mfma_kernel(
    const unsigned short* __restrict__ A, const unsigned short* __restrict__ W,
    const float* __restrict__ bias_a, const float* __restrict__ bias_b,
    float* __restrict__ Cout, int K, int m_base, int Mtot)
{
    __shared__ unsigned short As[128 * 32];
    __shared__ unsigned short Bs[128 * 32];

    const int tid = threadIdx.x;
    const int w   = tid >> 6;
    const int l   = tid & 63;
    const int wr  = w >> 1, wc = w & 1;
    const int lr  = l & 15, lk = l >> 4;

    const int m0 = blockIdx.x * 128;
    const int n0 = blockIdx.y * 128;

    f32x4 acc[4][4];
    #pragma unroll
    for (int i = 0; i < 4; ++i)
        #pragma unroll
        for (int j = 0; j < 4; ++j) acc[i][j] = (f32x4){0.f, 0.f, 0.f, 0.f};

    const int row_a0 = tid >> 2;
    const int cb     = (tid & 3) * 8;
    const unsigned short* aptr0 = A + (size_t)(m0 + row_a0) * K + cb;
    const unsigned short* aptr1 = A + (size_t)(m0 + row_a0 + 64) * K + cb;
    const unsigned short* bptr0 = W + (size_t)(n0 + row_a0) * K + cb;
    const unsigned short* bptr1 = W + (size_t)(n0 + row_a0 + 64) * K + cb;
    unsigned short* lA0 = &As[w * 512];
    unsigned short* lA1 = &As[2048 + w * 512];
    unsigned short* lB0 = &Bs[w * 512];
    unsigned short* lB1 = &Bs[2048 + w * 512];

    for (int k0 = 0; k0 < K; k0 += 32) {
        gload_lds16(aptr0 + k0, lA0);
        gload_lds16(aptr1 + k0, lA1);
        gload_lds16(bptr0 + k0, lB0);
        gload_lds16(bptr1 + k0, lB1);
        __syncthreads();

        bf16x8 af[4], bfr[4];
        #pragma unroll
        for (int i = 0; i < 4; ++i)
            af[i] = *reinterpret_cast<const bf16x8*>(&As[(wr * 64 + i * 16 + lr) * 32 + lk * 8]);
        #pragma unroll
        for (int j = 0; j < 4; ++j)
            bfr[j] = *reinterpret_cast<const bf16x8*>(&Bs[(wc * 64 + j * 16 + lr) * 32 + lk * 8]);
        #pragma unroll
        for (int i = 0; i < 4; ++i)
            #pragma unroll
            for (int j = 0; j < 4; ++j)
                acc[i][j] = __builtin_amdgcn_mfma_f32_16x16x32_bf16(af[i], bfr[j], acc[i][j], 0, 0, 0);
        __syncthreads();
    }

    #pragma unroll
    for (int i = 0; i < 4; ++i) {
        #pragma unroll
        for (int j = 0; j < 4; ++j) {
            int n = n0 + wc * 64 + j * 16 + lr;
            float ba = bias_a[n] + bias_b[n];
            int d = n >> 9, g = n & 511;
            #pragma unroll
            for (int r = 0; r < 4; ++r) {
                int m = m_base + m0 + wr * 64 + i * 16 + lk * 4 + r;
                Cout[((size_t)d * Mtot + m) * 512 + g] = acc[i][j][r] + ba;
            }
        }
    }
}

// ---------------------------------------------------------------------------
// MFMA-batched BiLSTM recurrence. 8 blocks = 2 dirs x 4 batch-groups of 16.
// 512 threads = 8 waves; wave w owns units w*16..+15, ALL 4 gates.
// Per step/wave: 16 x mfma_16x16x32_bf16 computes gates(16x(4x16)) =
// pre (C-in) + h(16x128)@Whh^T. Whh B-frags resident in registers all steps.
// h in LDS bf16, rows XOR-swizzled (hswz, write&read identical — rule 21).
// c in 4 registers/lane (i/f/gc/o of a cell land in the SAME lane by the
// C/D layout: col=lane&15=unit, row=(lane>>4)*4+r=batch).
// pre prefetched into regs 2 steps ahead; raw s_barrier with lgkmcnt(0)-only
// wait (T4: __syncthreads would drain vmcnt and kill the prefetch), memory
// clobber + sched_barrier(0) fences per rule 18.
// ---------------------------------------------------------------------------
template <typename OT>
__global__ __launch_bounds__(512) void lstm_kernel(
    const float* __restrict__ pre,           // [d][b][t][512]
    const unsigned short* __restrict__ Whb,  // [2][512][128] bf16
    OT* __restrict__ hout)                   // [b][t][256]
{
    const int d   = blockIdx.x >> 2;
    const int bg  = blockIdx.x & 3;
    const int tid = threadIdx.x;
    const int w   = tid >> 6;
    const int l   = tid & 63;
    const int lr  = l & 15;
    const int lk  = l >> 4;
    const int unit = w * 16 + lr;

    // B fragments: Whh[d][gate*128 + unit][kt*32 + lk*8 ..+7], 16 x bf16x8.
    bf16x8 bw[4][4];
    #pragma unroll
    for (int g = 0; g < 4; ++g)
        #pragma unroll
        for (int kt = 0; kt < 4; ++kt)
            bw[g][kt] = *reinterpret_cast<const bf16x8*>(
                Whb + ((size_t)d * 512 + g * 128 + unit) * 128 + kt * 32 + lk * 8);

    __shared__ unsigned short hbuf[2][16 * 128];   // [batch row=256B][unit], swizzled
    for (int i = tid; i < 1024; i += 512)
        reinterpret_cast<unsigned int*>(&hbuf[0][0])[i] = 0u;

    float cst[4] = {0.f, 0.f, 0.f, 0.f};

    // per-lane pre base: batch m = lk*4+r, gate g:
    // pre[((d*64 + bg*16 + m)*T + t)*512 + g*128 + unit]
    const float* pb = pre + ((size_t)(d * B_ + bg * 16) * T_) * 512 + unit;

    f32x4 pA[4], pB[4], pC[4];
    {   // prologue loads for t(0), t(1)
        int t0 = d ? (T_ - 1) : 0;
        int t1 = d ? (T_ - 2) : 1;
        #pragma unroll
        for (int g = 0; g < 4; ++g)
            #pragma unroll
            for (int r = 0; r < 4; ++r) {
                pA[g][r] = pb[((size_t)(lk * 4 + r) * T_ + t0) * 512 + g * 128];
                pB[g][r] = pb[((size_t)(lk * 4 + r) * T_ + t1) * 512 + g * 128];
            }
    }
    __syncthreads();   // h[0] zeros visible (one-time vmcnt drain: acceptable)

    int cur = 0;
    for (int s = 0; s < T_; ++s) {
        const int t = d ? (T_ - 1 - s) : s;

        // A fragments from h[cur] (swizzled reads)
        const char* hb = (const char*)&hbuf[cur][0];
        const int rowb = lr * 256;
        const int xo   = (lr & 7) << 4;
        bf16x8 a0 = *reinterpret_cast<const bf16x8*>(hb + rowb + ((0 * 64 + lk * 16) ^ xo));
        bf16x8 a1 = *reinterpret_cast<const bf16x8*>(hb + rowb + ((1 * 64 + lk * 16) ^ xo));
        bf16x8 a2 = *reinterpret_cast<const bf16x8*>(hb + rowb + ((2 * 64 + lk * 16) ^ xo));
        bf16x8 a3 = *reinterpret_cast<const bf16x8*>(hb + rowb + ((3 * 64 + lk * 16) ^ xo));

        // prefetch pre for step s+2 (consumed 2 steps later; spans barriers)
        if (s + 2 < T_) {
            int tn = d ? (T_ - 3 - s) : (s + 2);
            #pragma unroll
            for (int g = 0; g < 4; ++g)
                #pragma unroll
                for (int r = 0; r < 4; ++r)
                    pC[g][r] = pb[((size_t)(lk * 4 + r) * T_ + tn) * 512 + g * 128];
        }

        // gates = pre (C-in) + h @ Whh^T
        f32x4 acc[4];
        #pragma unroll
        for (int g = 0; g < 4; ++g) acc[g] = pA[g];
        #pragma unroll
        for (int g = 0; g < 4; ++g) {
            acc[g] = __builtin_amdgcn_mfma_f32_16x16x32_bf16(a0, bw[g][0], acc[g], 0, 0, 0);
            acc[g] = __builtin_amdgcn_mfma_f32_16x16x32_bf16(a1, bw[g][1], acc[g], 0, 0, 0);
            acc[g] = __builtin_amdgcn_mfma_f32_16x16x32_bf16(a2, bw[g][2], acc[g], 0, 0, 0);
            acc[g] = __builtin_amdgcn_mfma_f32_16x16x32_bf16(a3, bw[g][3], acc[g], 0, 0, 0);
        }

        // gate math: 4 cells/lane (unit, batch = lk*4+r); write h[nxt]
        char* hn = (char*)&hbuf[cur ^ 1][0];
        #pragma unroll
        for (int r = 0; r < 4; ++r) {
            float gi = acc[0][r], gf = acc[1][r], gv = acc[2][r], go = acc[3][r];
            cst[r] = sigmoidf_(gf) * cst[r] + sigmoidf_(gi) * tanhf(gv);
            float h = sigmoidf_(go) * tanhf(cst[r]);
            int m = lk * 4 + r;
            *(unsigned short*)(hn + m * 256 + hswz(m, unit * 2)) = f2bf(h);
            store_h(&hout[((size_t)(bg * 16 + m) * T_ + t) * 256 + d * 128 + unit], h);
        }

        #pragma unroll
        for (int g = 0; g < 4; ++g) { pA[g] = pB[g]; pB[g] = pC[g]; }

        asm volatile("s_waitcnt lgkmcnt(0)" ::: "memory");  // drain ds_writes only
        __builtin_amdgcn_s_barrier();
        __builtin_amdgcn_sched_barrier(0);                  // pin: no hoist past barrier
        cur ^= 1;
    }
}

// ---------------------------------------------------------------------------
// attention scores: block per (b, 32-t tile). Rows staged in LDS once.
// ---------------------------------------------------------------------------
__global__ __launch_bounds__(256) void attn_scores_kernel(
    const float* __restrict__ l1, const float* __restrict__ Wa1,
    const float* __restrict__ ba1, const float* __restrict__ Wa2,
    const float* __restrict__ ba2, float* __restrict__ scores)
{
    const int b   = blockIdx.x;
    const int t0  = blockIdx.y * 32;
    const int tid = threadIdx.x;
    const int j   = tid & 63, kq = tid >> 6;

    float w[64];
    const float* wsrc = Wa1 + j * 256 + kq * 64;
    #pragma unroll
    for (int k = 0; k < 64; ++k) w[k] = wsrc[k];

    __shared__ __align__(16) float rows[32 * 256];
    __shared__ float part[256];

    const float4* src = reinterpret_cast<const float4*>(
        l1 + (size_t)b * T_ * 256 + (size_t)t0 * 256);
    float4* dstv = reinterpret_cast<float4*>(rows);
    #pragma unroll
    for (int q = 0; q < 8; ++q) dstv[q * 256 + tid] = src[q * 256 + tid];

    float wa2 = (tid < 64) ? Wa2[tid] : 0.f;
    float bj  = (tid < 64) ? ba1[tid] : 0.f;
    float bb2 = ba2[0];
    __syncthreads();

    for (int tl = 0; tl < 32; ++tl) {
        const float* row = &rows[tl * 256 + kq * 64];
        float acc = 0.f;
        #pragma unroll
        for (int k4 = 0; k4 < 16; ++k4) {
            float4 hv = *reinterpret_cast<const float4*>(&row[k4 * 4]);
            acc += w[k4 * 4 + 0] * hv.x + w[k4 * 4 + 1] * hv.y
                 + w[k4 * 4 + 2] * hv.z + w[k4 * 4 + 3] * hv.w;
        }
        part[tid] = acc;
        __syncthreads();
        if (tid < 64) {
            float dj = part[tid] + part[tid + 64] + part[tid + 128] + part[tid + 192];
            float sv = tanhf(dj + bj) * wa2;
            #pragma unroll
            for (int off = 32; off > 0; off >>= 1) sv += __shfl_xor(sv, off);
            if (tid == 0) scores[b * T_ + t0 + tl] = sv + bb2;
        }
        __syncthreads();
    }
}

// ---------------------------------------------------------------------------
// softmax + context + classifier head: block per b.
// ---------------------------------------------------------------------------
__global__ __launch_bounds__(256) void attn_head_kernel(
    const float* __restrict__ l1, const float* __restrict__ scores,
    const float* __restrict__ Wc1, const float* __restrict__ bc1,
    const float* __restrict__ Wc2, const float* __restrict__ bc2,
    float* __restrict__ out)
{
    const int b   = blockIdx.x;
    const int tid = threadIdx.x;
    __shared__ float wsl[256];
    __shared__ float red[8];
    __shared__ float ctx[256];
    __shared__ float hid[128];
    __shared__ float wc1s[128 * 65];

    float v = scores[b * T_ + tid];
    float mx = v;
    #pragma unroll
    for (int off = 32; off > 0; off >>= 1) mx = fmaxf(mx, __shfl_xor(mx, off));
    if ((tid & 63) == 0) red[tid >> 6] = mx;
    __syncthreads();
    mx = fmaxf(fmaxf(red[0], red[1]), fmaxf(red[2], red[3]));
    float e = expf(v - mx);
    float s = e;
    #pragma unroll
    for (int off = 32; off > 0; off >>= 1) s += __shfl_xor(s, off);
    if ((tid & 63) == 0) red[4 + (tid >> 6)] = s;
    __syncthreads();
    float denom = red[4] + red[5] + red[6] + red[7];
    wsl[tid] = e / denom;
    __syncthreads();

    float acc = 0.f;
    const float* lb = l1 + (size_t)b * T_ * 256 + tid;
    #pragma unroll 4
    for (int t = 0; t < T_; ++t) acc += lb[(size_t)t * 256] * wsl[t];
    ctx[tid] = acc;
    __syncthreads();

    float hacc = (tid < 128) ? bc1[tid] : 0.f;
    for (int kb = 0; kb < 4; ++kb) {
        for (int i = tid; i < 128 * 64; i += 256) {
            int jj = i >> 6, kk = i & 63;
            wc1s[jj * 65 + kk] = Wc1[jj * 256 + kb * 64 + kk];
        }
        __syncthreads();
        if (tid < 128) {
            #pragma unroll
            for (int kk = 0; kk < 64; ++kk)
                hacc += ctx[kb * 64 + kk] * wc1s[tid * 65 + kk];
        }
        __syncthreads();
    }
    if (tid < 128) hid[tid] = fmaxf(hacc, 0.f);
    __syncthreads();

    if (tid < NC_) {
        float a = bc2[tid];
        #pragma unroll
        for (int k = 0; k < 128; ++k) a += hid[k] * Wc2[tid * 128 + k];
        out[b * NC_ + tid] = a;
    }
}

// ---------------------------------------------------------------------------
extern "C" void kernel_launch(void* const* d_in, const int* in_sizes, int n_in,
                              void* d_out, int out_size, void* d_ws, size_t ws_size,
                              hipStream_t stream)
{
    const float* x    = (const float*)d_in[0];
    const float* adj  = (const float*)d_in[1];
    const float* Wg1  = (const float*)d_in[2];
    const float* bg1  = (const float*)d_in[3];
    const float* Wg2  = (const float*)d_in[4];
    const float* bg2  = (const float*)d_in[5];
    const float* Wih0 = (const float*)d_in[6];
    const float* Whh0 = (const float*)d_in[7];
    const float* bih0 = (const float*)d_in[8];
    const float* bhh0 = (const float*)d_in[9];
    const float* Wih1 = (const float*)d_in[10];
    const float* Whh1 = (const float*)d_in[11];
    const float* bih1 = (const float*)d_in[12];
    const float* bhh1 = (const float*)d_in[13];
    const float* Wa1  = (const float*)d_in[14];
    const float* ba1  = (const float*)d_in[15];
    const float* Wa2  = (const float*)d_in[16];
    const float* ba2  = (const float*)d_in[17];
    const float* Wc1  = (const float*)d_in[18];
    const float* bc1  = (const float*)d_in[19];
    const float* Wc2  = (const float*)d_in[20];
    const float* bc2  = (const float*)d_in[21];

    char* ws = (char*)d_ws;
    // Workspace (bytes). Peak 156,946,432 < 160,432,128 proven by round-1 pass.
    unsigned short* seqb = (unsigned short*)(ws);
    unsigned short* l0b  = (unsigned short*)(ws);
    float*          l1f  = (float*)(ws + 8388608);
    float*          scr  = (float*)(ws + 25165824);
    unsigned short* H1W  = (unsigned short*)(ws + 64000000);
    unsigned short* adjb = (unsigned short*)(ws + 80777216);
    unsigned short* w2b  = (unsigned short*)(ws + 80785408);
    float*          pre  = (float*)(ws + 80793600);
    unsigned short* W0b  = (unsigned short*)(ws + 147902464);
    unsigned short* W1b  = (unsigned short*)(ws + 155897856);
    unsigned short* W0hb = (unsigned short*)(ws + 156422144);   // 262,144 B
    unsigned short* W1hb = (unsigned short*)(ws + 156684288);   // 262,144 B

    const int n0e = in_sizes[6];    // 2*512*3904
    const int n1e = in_sizes[10];   // 2*512*256
    const int h0e = in_sizes[7];    // 2*512*128
    const int h1e = in_sizes[11];   // 2*512*128
    cvt_bf16_kernel<<<(n0e / 4 + 255) / 256, 256, 0, stream>>>(Wih0, W0b, n0e / 4);
    cvt_bf16_kernel<<<(n1e / 4 + 255) / 256, 256, 0, stream>>>(Wih1, W1b, n1e / 4);
    cvt_bf16_kernel<<<(h0e / 4 + 255) / 256, 256, 0, stream>>>(Whh0, W0hb, h0e / 4);
    cvt_bf16_kernel<<<(h1e / 4 + 255) / 256, 256, 0, stream>>>(Whh1, W1hb, h1e / 4);
    cvt_adj_kernel<<<16, 256, 0, stream>>>(adj, adjb);
    cvt_w2_kernel <<<16, 256, 0, stream>>>(Wg2, w2b);

    for (int ch = 0; ch < 2; ++ch) {
        int m_base = ch * CHUNK_M;
        for (int sc = 0; sc < CHUNK_M / SUB_M; ++sc) {
            gcn_h1_kernel<<<SUB_M, 256, 0, stream>>>(
                x, adj, Wg1, bg1, H1W, m_base + sc * SUB_M);
            gcn_mix_kernel<<<SUB_M / 2, 256, 0, stream>>>(
                H1W, adjb, w2b, bg2, seqb, sc * SUB_M);
        }
        gemm_mfma_kernel<<<dim3(CHUNK_M / 128, 8), 256, 0, stream>>>(
            seqb, W0b, bih0, bhh0, pre, NG_, m_base, M_TOT);
    }
    lstm_kernel<<<8, 512, 0, stream>>>(pre, W0hb, l0b);
    gemm_mfma_kernel<<<dim3(M_TOT / 128, 8), 256, 0, stream>>>(
        l0b, W1b, bih1, bhh1, pre, 256, 0, M_TOT);
    lstm_kernel<<<8, 512, 0, stream>>>(pre, W1hb, l1f);
    attn_scores_kernel<<<dim3(B_, 8), 256, 0, stream>>>(l1f, Wa1, ba1, Wa2, ba2, scr);
    attn_head_kernel<<<B_, 256, 0, stream>>>(l1f, scr, Wc1, bc1, Wc2, bc2, (float*)d_out);
}

// Round 14
// 1573.438 us; speedup vs baseline: 1.1104x; 1.1104x over previous
//
#include <hip/hip_runtime.h>
#include <math.h>

#define B_    64
#define T_    256
#define N_    61
#define FIN_  3
#define GH_   64
#define LH_   128
#define NC_   10
#define NG_   3904      /* N_*GH_ */
#define M_TOT 16384     /* B_*T_  */
#define CHUNK_M 8192
#define SUB_M   2048    /* GCN sub-chunk */

typedef __attribute__((ext_vector_type(8))) short bf16x8;
typedef __attribute__((ext_vector_type(4))) float f32x4;

__device__ __forceinline__ float gelu_exact(float x) {
    return 0.5f * x * (1.0f + erff(x * 0.70710678118654752f));
}
__device__ __forceinline__ float sigmoidf_(float x) {
    return 1.0f / (1.0f + expf(-x));
}
__device__ __forceinline__ unsigned short f2bf(float f) {
    unsigned int u = __float_as_uint(f);
    u = (u + 0x7FFFu + ((u >> 16) & 1u)) >> 16;
    return (unsigned short)u;
}
__device__ __forceinline__ void store_h(float* p, float v) { *p = v; }
__device__ __forceinline__ void store_h(unsigned short* p, float v) { *p = f2bf(v); }

__device__ __forceinline__ void gload_lds16(const void* g, void* l) {
    __builtin_amdgcn_global_load_lds(
        (const __attribute__((address_space(1))) unsigned int*)g,
        (__attribute__((address_space(3))) unsigned int*)l,
        16, 0, 0);
}

// Shared 64-elem-row swizzle: XOR k with (row&3)*16. Used identically by every
// writer (global pre-swizzle) and reader (LDS frag read) — both-sides-or-neither.
__device__ __forceinline__ int swz(int row, int k) { return k ^ ((row & 3) << 4); }

// byte-level row swizzle for 256B bf16 rows (T2): same map on write and read.
__device__ __forceinline__ int hswz(int row, int byteoff) { return byteoff ^ ((row & 7) << 4); }

// ---------------------------------------------------------------------------
// fp32 -> bf16 weight conversion (4 elems/thread). n4 = ELEMENT count / 4.
// ---------------------------------------------------------------------------
__global__ __launch_bounds__(256) void cvt_bf16_kernel(
    const float* __restrict__ in, unsigned short* __restrict__ out, int n4)
{
    int i = blockIdx.x * 256 + threadIdx.x;
    if (i < n4) {
        float4 v = reinterpret_cast<const float4*>(in)[i];
        ushort4 o;
        o.x = f2bf(v.x); o.y = f2bf(v.y); o.z = f2bf(v.z); o.w = f2bf(v.w);
        reinterpret_cast<ushort4*>(out)[i] = o;
    }
}

// adj (61x61 fp32) -> adjb (64x64 bf16, zero-padded, pre-swizzled). grid 16.
__global__ __launch_bounds__(256) void cvt_adj_kernel(
    const float* __restrict__ adj, unsigned short* __restrict__ adjb)
{
    int i = blockIdx.x * 256 + threadIdx.x;
    if (i < 4096) {
        int n = i >> 6, m = i & 63;
        unsigned short v = (n < N_ && m < N_) ? f2bf(adj[n * N_ + m]) : (unsigned short)0;
        adjb[n * 64 + swz(n, m)] = v;
    }
}

// W2 (64x64 fp32) -> w2b (64x64 bf16, pre-swizzled). grid 16.
__global__ __launch_bounds__(256) void cvt_w2_kernel(
    const float* __restrict__ W2, unsigned short* __restrict__ w2b)
{
    int i = blockIdx.x * 256 + threadIdx.x;
    if (i < 4096) {
        int c = i >> 6, f = i & 63;
        w2b[c * 64 + swz(c, f)] = f2bf(W2[c * 64 + f]);
    }
}

// ---------------------------------------------------------------------------
// GCN K1: per (b,t): AX = A@X (fp32), H1 = gelu(AX @ W1^T + b1).
// Writes H1W bf16 TRANSPOSED [btl*64+c][m], m=61..63 zeroed, pre-swizzled.
// ---------------------------------------------------------------------------
__global__ __launch_bounds__(256) void gcn_h1_kernel(
    const float* __restrict__ x, const float* __restrict__ adj,
    const float* __restrict__ W1, const float* __restrict__ b1,
    unsigned short* __restrict__ H1W, int bt_base)
{
    __shared__ float adjs[N_ * 65];
    __shared__ float h1s [N_ * 65];
    __shared__ float xs [184];
    __shared__ float axs[184];
    __shared__ float w1s[192];
    __shared__ float b1s[64];

    const int tid = threadIdx.x;
    const int bt  = bt_base + blockIdx.x;

    for (int i = tid; i < N_ * N_; i += 256) {
        int n = i / 61, m = i - n * 61;
        adjs[n * 65 + m] = adj[i];
    }
    for (int i = tid; i < N_ * FIN_; i += 256) xs[i] = x[(size_t)bt * (N_ * FIN_) + i];
    for (int i = tid; i < GH_ * FIN_; i += 256) w1s[i] = W1[i];
    if (tid < GH_) b1s[tid] = b1[tid];
    __syncthreads();

    if (tid < N_ * FIN_) {
        int n = tid / 3, f = tid - n * 3;
        float acc = 0.f;
        for (int m = 0; m < N_; ++m) acc += adjs[n * 65 + m] * xs[m * 3 + f];
        axs[tid] = acc;
    }
    __syncthreads();

    for (int u = 0; u < 16; ++u) {
        int idx = tid + u * 256;
        if (idx < N_ * GH_) {
            int m = idx >> 6, c = idx & 63;
            float acc = b1s[c];
            acc += axs[m * 3 + 0] * w1s[c * 3 + 0];
            acc += axs[m * 3 + 1] * w1s[c * 3 + 1];
            acc += axs[m * 3 + 2] * w1s[c * 3 + 2];
            h1s[m * 65 + c] = gelu_exact(acc);
        }
    }
    __syncthreads();

    unsigned short* dst = H1W + (size_t)blockIdx.x * 4096;
    for (int i = tid; i < 4096; i += 256) {
        int c = i >> 6, m = i & 63;
        unsigned short v = (m < N_) ? f2bf(h1s[m * 65 + c]) : (unsigned short)0;
        dst[c * 64 + swz(c, m)] = v;
    }
}

// ---------------------------------------------------------------------------
// GCN K23: per block = 2 consecutive bt. MFMA both heavy stages.
// ---------------------------------------------------------------------------
__global__ __launch_bounds__(256) void gcn_mix_kernel(
    const unsigned short* __restrict__ H1W,
    const unsigned short* __restrict__ adjb,
    const unsigned short* __restrict__ w2b,
    const float* __restrict__ b2,
    unsigned short* __restrict__ seqc,
    int sc_base)
{
    __shared__ unsigned short adjbs[64 * 64];
    __shared__ unsigned short b1t [128 * 64];
    __shared__ unsigned short w2bs[64 * 64];
    __shared__ unsigned short T   [128 * 64];
    __shared__ float b2s[64];

    const int tid = threadIdx.x;
    const int w   = tid >> 6;
    const int l   = tid & 63;
    const int lr  = l & 15, lk = l >> 4;
    const int p   = blockIdx.x;

    #pragma unroll
    for (int q = 0; q < 2; ++q)
        gload_lds16(adjb + q * 2048 + w * 512 + l * 8, &adjbs[q * 2048 + w * 512]);
    #pragma unroll
    for (int q = 0; q < 2; ++q)
        gload_lds16(w2b + q * 2048 + w * 512 + l * 8, &w2bs[q * 2048 + w * 512]);
    #pragma unroll
    for (int q = 0; q < 4; ++q)
        gload_lds16(H1W + (size_t)p * 8192 + q * 2048 + w * 512 + l * 8,
                    &b1t[q * 2048 + w * 512]);
    if (tid < 64) b2s[tid] = b2[tid];
    __syncthreads();

    f32x4 acc1[4][2];
    #pragma unroll
    for (int i = 0; i < 4; ++i)
        #pragma unroll
        for (int j = 0; j < 2; ++j) acc1[i][j] = (f32x4){0.f, 0.f, 0.f, 0.f};

    #pragma unroll
    for (int kk = 0; kk < 2; ++kk) {
        const int kb = kk * 32 + lk * 8;
        bf16x8 af[4], bfr[2];
        #pragma unroll
        for (int i = 0; i < 4; ++i) {
            int rn = i * 16 + lr;
            af[i] = *reinterpret_cast<const bf16x8*>(&adjbs[rn * 64 + swz(rn, kb)]);
        }
        #pragma unroll
        for (int j = 0; j < 2; ++j) {
            int rb = w * 32 + j * 16 + lr;
            bfr[j] = *reinterpret_cast<const bf16x8*>(&b1t[rb * 64 + swz(rb, kb)]);
        }
        #pragma unroll
        for (int i = 0; i < 4; ++i)
            #pragma unroll
            for (int j = 0; j < 2; ++j)
                acc1[i][j] = __builtin_amdgcn_mfma_f32_16x16x32_bf16(af[i], bfr[j], acc1[i][j], 0, 0, 0);
    }

    #pragma unroll
    for (int i = 0; i < 4; ++i) {
        #pragma unroll
        for (int j = 0; j < 2; ++j) {
            int col = w * 32 + j * 16 + lr;
            int c   = col & 63;
            int rbase = (col >> 6) * 64;
            #pragma unroll
            for (int r = 0; r < 4; ++r) {
                int n   = i * 16 + lk * 4 + r;
                int row = rbase + n;
                T[row * 64 + swz(row, c)] = f2bf(acc1[i][j][r]);
            }
        }
    }
    __syncthreads();

    f32x4 acc2[2][4];
    #pragma unroll
    for (int i = 0; i < 2; ++i)
        #pragma unroll
        for (int j = 0; j < 4; ++j) acc2[i][j] = (f32x4){0.f, 0.f, 0.f, 0.f};

    #pragma unroll
    for (int kk = 0; kk < 2; ++kk) {
        const int kb = kk * 32 + lk * 8;
        bf16x8 a2[2], bw[4];
        #pragma unroll
        for (int i = 0; i < 2; ++i) {
            int r2 = w * 32 + i * 16 + lr;
            a2[i] = *reinterpret_cast<const bf16x8*>(&T[r2 * 64 + swz(r2, kb)]);
        }
        #pragma unroll
        for (int j = 0; j < 4; ++j) {
            int co = j * 16 + lr;
            bw[j] = *reinterpret_cast<const bf16x8*>(&w2bs[co * 64 + swz(co, kb)]);
        }
        #pragma unroll
        for (int i = 0; i < 2; ++i)
            #pragma unroll
            for (int j = 0; j < 4; ++j)
                acc2[i][j] = __builtin_amdgcn_mfma_f32_16x16x32_bf16(a2[i], bw[j], acc2[i][j], 0, 0, 0);
    }

    #pragma unroll
    for (int i = 0; i < 2; ++i) {
        #pragma unroll
        for (int j = 0; j < 4; ++j) {
            int co = j * 16 + lr;
            float bias = b2s[co];
            #pragma unroll
            for (int r = 0; r < 4; ++r) {
                int row = w * 32 + i * 16 + lk * 4 + r;
                int n   = row & 63;
                if (n < N_) {
                    int btc = sc_base + p * 2 + (row >> 6);
                    seqc[(size_t)btc * NG_ + n * 64 + co] =
                        f2bf(gelu_exact(acc2[i][j][r] + bias));
                }
            }
        }
    }
}

// ---------------------------------------------------------------------------
// bf16 MFMA GEMM: C = A(Mc x K) @ W(1024 x K)^T + bias_a + bias_b
// ---------------------------------------------------------------------------
__global__ __launch_bounds__(256) void gemm_mfma_kernel(
    const unsigned short* __restrict__ A, const unsigned short* __restrict__ W,
    const float* __restrict__ bias_a, const float* __restrict__ bias_b,
    float* __restrict__ Cout, int K, int m_base, int Mtot)
{
    __shared__ unsigned short As[128 * 32];
    __shared__ unsigned short Bs[128 * 32];

    const int tid = threadIdx.x;
    const int w   = tid >> 6;
    const int l   = tid & 63;
    const int wr  = w >> 1, wc = w & 1;
    const int lr  = l & 15, lk = l >> 4;

    const int m0 = blockIdx.x * 128;
    const int n0 = blockIdx.y * 128;

    f32x4 acc[4][4];
    #pragma unroll
    for (int i = 0; i < 4; ++i)
        #pragma unroll
        for (int j = 0; j < 4; ++j) acc[i][j] = (f32x4){0.f, 0.f, 0.f, 0.f};

    const int row_a0 = tid >> 2;
    const int cb     = (tid & 3) * 8;
    const unsigned short* aptr0 = A + (size_t)(m0 + row_a0) * K + cb;
    const unsigned short* aptr1 = A + (size_t)(m0 + row_a0 + 64) * K + cb;
    const unsigned short* bptr0 = W + (size_t)(n0 + row_a0) * K + cb;
    const unsigned short* bptr1 = W + (size_t)(n0 + row_a0 + 64) * K + cb;
    unsigned short* lA0 = &As[w * 512];
    unsigned short* lA1 = &As[2048 + w * 512];
    unsigned short* lB0 = &Bs[w * 512];
    unsigned short* lB1 = &Bs[2048 + w * 512];

    for (int k0 = 0; k0 < K; k0 += 32) {
        gload_lds16(aptr0 + k0, lA0);
        gload_lds16(aptr1 + k0, lA1);
        gload_lds16(bptr0 + k0, lB0);
        gload_lds16(bptr1 + k0, lB1);
        __syncthreads();

        bf16x8 af[4], bfr[4];
        #pragma unroll
        for (int i = 0; i < 4; ++i)
            af[i] = *reinterpret_cast<const bf16x8*>(&As[(wr * 64 + i * 16 + lr) * 32 + lk * 8]);
        #pragma unroll
        for (int j = 0; j < 4; ++j)
            bfr[j] = *reinterpret_cast<const bf16x8*>(&Bs[(wc * 64 + j * 16 + lr) * 32 + lk * 8]);
        #pragma unroll
        for (int i = 0; i < 4; ++i)
            #pragma unroll
            for (int j = 0; j < 4; ++j)
                acc[i][j] = __builtin_amdgcn_mfma_f32_16x16x32_bf16(af[i], bfr[j], acc[i][j], 0, 0, 0);
        __syncthreads();
    }

    #pragma unroll
    for (int i = 0; i < 4; ++i) {
        #pragma unroll
        for (int j = 0; j < 4; ++j) {
            int n = n0 + wc * 64 + j * 16 + lr;
            float ba = bias_a[n] + bias_b[n];
            int d = n >> 9, g = n & 511;
            #pragma unroll
            for (int r = 0; r < 4; ++r) {
                int m = m_base + m0 + wr * 64 + i * 16 + lk * 4 + r;
                Cout[((size_t)d * Mtot + m) * 512 + g] = acc[i][j][r] + ba;
            }
        }
    }
}

// ---------------------------------------------------------------------------
// MFMA-batched BiLSTM recurrence, SOFTWARE-PIPELINED (r13 datapath, fixed
// prefetch). 8 blocks = 2 dirs x 4 batch-groups of 16; 512 threads = 8 waves.
// Time loop unrolled x2 with STATIC register sets pE/pO: even step consumes
// pE and reloads pE for s+2 (no register rotation -> the vmcnt wait for a
// load lands ~2 step-bodies (~1000+ cyc) after issue, covering HBM latency.
// r13's rotation pA=pB;pB=pC forced a same-step vmcnt wait = ~5500 cyc/step).
// Raw s_barrier + lgkmcnt(0)-only wait (T4) keeps prefetch in flight across
// the barrier; sched_barrier(0) per rule 18.
// ---------------------------------------------------------------------------
#define LSTM_STEP(S, PUSE)                                                          \
    {                                                                               \
        const int t_ = d ? (T_ - 1 - (S)) : (S);                                    \
        const char* hb_ = (const char*)&hbuf[cur][0];                               \
        const int rowb_ = lr * 256;                                                 \
        const int xo_   = (lr & 7) << 4;                                            \
        bf16x8 a0 = *reinterpret_cast<const bf16x8*>(hb_ + rowb_ + ((0 * 64 + lk * 16) ^ xo_)); \
        bf16x8 a1 = *reinterpret_cast<const bf16x8*>(hb_ + rowb_ + ((1 * 64 + lk * 16) ^ xo_)); \
        bf16x8 a2 = *reinterpret_cast<const bf16x8*>(hb_ + rowb_ + ((2 * 64 + lk * 16) ^ xo_)); \
        bf16x8 a3 = *reinterpret_cast<const bf16x8*>(hb_ + rowb_ + ((3 * 64 + lk * 16) ^ xo_)); \
        f32x4 acc_[4];                                                              \
        _Pragma("unroll")                                                           \
        for (int g_ = 0; g_ < 4; ++g_) acc_[g_] = PUSE[g_];                         \
        if ((S) + 2 < T_) {                                                         \
            int tn_ = d ? (T_ - 3 - (S)) : ((S) + 2);                               \
            _Pragma("unroll")                                                       \
            for (int g_ = 0; g_ < 4; ++g_)                                          \
                _Pragma("unroll")                                                   \
                for (int r_ = 0; r_ < 4; ++r_)                                      \
                    PUSE[g_][r_] = pb[((size_t)(lk * 4 + r_) * T_ + tn_) * 512 + g_ * 128]; \
        }                                                                           \
        _Pragma("unroll")                                                           \
        for (int g_ = 0; g_ < 4; ++g_) {                                            \
            acc_[g_] = __builtin_amdgcn_mfma_f32_16x16x32_bf16(a0, bw[g_][0], acc_[g_], 0, 0, 0); \
            acc_[g_] = __builtin_amdgcn_mfma_f32_16x16x32_bf16(a1, bw[g_][1], acc_[g_], 0, 0, 0); \
            acc_[g_] = __builtin_amdgcn_mfma_f32_16x16x32_bf16(a2, bw[g_][2], acc_[g_], 0, 0, 0); \
            acc_[g_] = __builtin_amdgcn_mfma_f32_16x16x32_bf16(a3, bw[g_][3], acc_[g_], 0, 0, 0); \
        }                                                                           \
        char* hn_ = (char*)&hbuf[cur ^ 1][0];                                       \
        _Pragma("unroll")                                                           \
        for (int r_ = 0; r_ < 4; ++r_) {                                            \
            float gi_ = acc_[0][r_], gf_ = acc_[1][r_];                             \
            float gv_ = acc_[2][r_], go_ = acc_[3][r_];                             \
            cst[r_] = sigmoidf_(gf_) * cst[r_] + sigmoidf_(gi_) * tanhf(gv_);       \
            float h_ = sigmoidf_(go_) * tanhf(cst[r_]);                             \
            int m_ = lk * 4 + r_;                                                   \
            *(unsigned short*)(hn_ + m_ * 256 + hswz(m_, unit * 2)) = f2bf(h_);     \
            store_h(&hout[((size_t)(bg * 16 + m_) * T_ + t_) * 256 + d * 128 + unit], h_); \
        }                                                                           \
        asm volatile("s_waitcnt lgkmcnt(0)" ::: "memory");                          \
        __builtin_amdgcn_s_barrier();                                               \
        __builtin_amdgcn_sched_barrier(0);                                          \
        cur ^= 1;                                                                   \
    }

template <typename OT>
__global__ __launch_bounds__(512) void lstm_kernel(
    const float* __restrict__ pre,           // [d][b][t][512]
    const unsigned short* __restrict__ Whb,  // [2][512][128] bf16
    OT* __restrict__ hout)                   // [b][t][256]
{
    const int d   = blockIdx.x >> 2;
    const int bg  = blockIdx.x & 3;
    const int tid = threadIdx.x;
    const int w   = tid >> 6;
    const int l   = tid & 63;
    const int lr  = l & 15;
    const int lk  = l >> 4;
    const int unit = w * 16 + lr;

    // B fragments: Whh[d][gate*128 + unit][kt*32 + lk*8 ..+7], 16 x bf16x8.
    bf16x8 bw[4][4];
    #pragma unroll
    for (int g = 0; g < 4; ++g)
        #pragma unroll
        for (int kt = 0; kt < 4; ++kt)
            bw[g][kt] = *reinterpret_cast<const bf16x8*>(
                Whb + ((size_t)d * 512 + g * 128 + unit) * 128 + kt * 32 + lk * 8);

    __shared__ unsigned short hbuf[2][16 * 128];   // [batch row=256B][unit], swizzled
    for (int i = tid; i < 1024; i += 512)
        reinterpret_cast<unsigned int*>(&hbuf[0][0])[i] = 0u;

    float cst[4] = {0.f, 0.f, 0.f, 0.f};

    // per-lane pre base: batch m = lk*4+r, gate g:
    // pre[((d*64 + bg*16 + m)*T + t)*512 + g*128 + unit]
    const float* pb = pre + ((size_t)(d * B_ + bg * 16) * T_) * 512 + unit;

    f32x4 pE[4], pO[4];
    {   // prologue loads for t(0), t(1)
        int t0 = d ? (T_ - 1) : 0;
        int t1 = d ? (T_ - 2) : 1;
        #pragma unroll
        for (int g = 0; g < 4; ++g)
            #pragma unroll
            for (int r = 0; r < 4; ++r) {
                pE[g][r] = pb[((size_t)(lk * 4 + r) * T_ + t0) * 512 + g * 128];
                pO[g][r] = pb[((size_t)(lk * 4 + r) * T_ + t1) * 512 + g * 128];
            }
    }
    __syncthreads();   // h[0] zeros visible (one-time full drain: acceptable)

    int cur = 0;
    for (int s = 0; s < T_; s += 2) {
        LSTM_STEP(s,     pE);
        LSTM_STEP(s + 1, pO);
    }
}

// ---------------------------------------------------------------------------
// attention scores: block per (b, 32-t tile). Rows staged in LDS once.
// ---------------------------------------------------------------------------
__global__ __launch_bounds__(256) void attn_scores_kernel(
    const float* __restrict__ l1, const float* __restrict__ Wa1,
    const float* __restrict__ ba1, const float* __restrict__ Wa2,
    const float* __restrict__ ba2, float* __restrict__ scores)
{
    const int b   = blockIdx.x;
    const int t0  = blockIdx.y * 32;
    const int tid = threadIdx.x;
    const int j   = tid & 63, kq = tid >> 6;

    float w[64];
    const float* wsrc = Wa1 + j * 256 + kq * 64;
    #pragma unroll
    for (int k = 0; k < 64; ++k) w[k] = wsrc[k];

    __shared__ __align__(16) float rows[32 * 256];
    __shared__ float part[256];

    const float4* src = reinterpret_cast<const float4*>(
        l1 + (size_t)b * T_ * 256 + (size_t)t0 * 256);
    float4* dstv = reinterpret_cast<float4*>(rows);
    #pragma unroll
    for (int q = 0; q < 8; ++q) dstv[q * 256 + tid] = src[q * 256 + tid];

    float wa2 = (tid < 64) ? Wa2[tid] : 0.f;
    float bj  = (tid < 64) ? ba1[tid] : 0.f;
    float bb2 = ba2[0];
    __syncthreads();

    for (int tl = 0; tl < 32; ++tl) {
        const float* row = &rows[tl * 256 + kq * 64];
        float acc = 0.f;
        #pragma unroll
        for (int k4 = 0; k4 < 16; ++k4) {
            float4 hv = *reinterpret_cast<const float4*>(&row[k4 * 4]);
            acc += w[k4 * 4 + 0] * hv.x + w[k4 * 4 + 1] * hv.y
                 + w[k4 * 4 + 2] * hv.z + w[k4 * 4 + 3] * hv.w;
        }
        part[tid] = acc;
        __syncthreads();
        if (tid < 64) {
            float dj = part[tid] + part[tid + 64] + part[tid + 128] + part[tid + 192];
            float sv = tanhf(dj + bj) * wa2;
            #pragma unroll
            for (int off = 32; off > 0; off >>= 1) sv += __shfl_xor(sv, off);
            if (tid == 0) scores[b * T_ + t0 + tl] = sv + bb2;
        }
        __syncthreads();
    }
}

// ---------------------------------------------------------------------------
// softmax + context + classifier head: block per b.
// ---------------------------------------------------------------------------
__global__ __launch_bounds__(256) void attn_head_kernel(
    const float* __restrict__ l1, const float* __restrict__ scores,
    const float* __restrict__ Wc1, const float* __restrict__ bc1,
    const float* __restrict__ Wc2, const float* __restrict__ bc2,
    float* __restrict__ out)
{
    const int b   = blockIdx.x;
    const int tid = threadIdx.x;
    __shared__ float wsl[256];
    __shared__ float red[8];
    __shared__ float ctx[256];
    __shared__ float hid[128];
    __shared__ float wc1s[128 * 65];

    float v = scores[b * T_ + tid];
    float mx = v;
    #pragma unroll
    for (int off = 32; off > 0; off >>= 1) mx = fmaxf(mx, __shfl_xor(mx, off));
    if ((tid & 63) == 0) red[tid >> 6] = mx;
    __syncthreads();
    mx = fmaxf(fmaxf(red[0], red[1]), fmaxf(red[2], red[3]));
    float e = expf(v - mx);
    float s = e;
    #pragma unroll
    for (int off = 32; off > 0; off >>= 1) s += __shfl_xor(s, off);
    if ((tid & 63) == 0) red[4 + (tid >> 6)] = s;
    __syncthreads();
    float denom = red[4] + red[5] + red[6] + red[7];
    wsl[tid] = e / denom;
    __syncthreads();

    float acc = 0.f;
    const float* lb = l1 + (size_t)b * T_ * 256 + tid;
    #pragma unroll 4
    for (int t = 0; t < T_; ++t) acc += lb[(size_t)t * 256] * wsl[t];
    ctx[tid] = acc;
    __syncthreads();

    float hacc = (tid < 128) ? bc1[tid] : 0.f;
    for (int kb = 0; kb < 4; ++kb) {
        for (int i = tid; i < 128 * 64; i += 256) {
            int jj = i >> 6, kk = i & 63;
            wc1s[jj * 65 + kk] = Wc1[jj * 256 + kb * 64 + kk];
        }
        __syncthreads();
        if (tid < 128) {
            #pragma unroll
            for (int kk = 0; kk < 64; ++kk)
                hacc += ctx[kb * 64 + kk] * wc1s[tid * 65 + kk];
        }
        __syncthreads();
    }
    if (tid < 128) hid[tid] = fmaxf(hacc, 0.f);
    __syncthreads();

    if (tid < NC_) {
        float a = bc2[tid];
        #pragma unroll
        for (int k = 0; k < 128; ++k) a += hid[k] * Wc2[tid * 128 + k];
        out[b * NC_ + tid] = a;
    }
}

// ---------------------------------------------------------------------------
extern "C" void kernel_launch(void* const* d_in, const int* in_sizes, int n_in,
                              void* d_out, int out_size, void* d_ws, size_t ws_size,
                              hipStream_t stream)
{
    const float* x    = (const float*)d_in[0];
    const float* adj  = (const float*)d_in[1];
    const float* Wg1  = (const float*)d_in[2];
    const float* bg1  = (const float*)d_in[3];
    const float* Wg2  = (const float*)d_in[4];
    const float* bg2  = (const float*)d_in[5];
    const float* Wih0 = (const float*)d_in[6];
    const float* Whh0 = (const float*)d_in[7];
    const float* bih0 = (const float*)d_in[8];
    const float* bhh0 = (const float*)d_in[9];
    const float* Wih1 = (const float*)d_in[10];
    const float* Whh1 = (const float*)d_in[11];
    const float* bih1 = (const float*)d_in[12];
    const float* bhh1 = (const float*)d_in[13];
    const float* Wa1  = (const float*)d_in[14];
    const float* ba1  = (const float*)d_in[15];
    const float* Wa2  = (const float*)d_in[16];
    const float* ba2  = (const float*)d_in[17];
    const float* Wc1  = (const float*)d_in[18];
    const float* bc1  = (const float*)d_in[19];
    const float* Wc2  = (const float*)d_in[20];
    const float* bc2  = (const float*)d_in[21];

    char* ws = (char*)d_ws;
    // Workspace (bytes). Peak 156,946,432 < 160,432,128 proven by round-1 pass.
    unsigned short* seqb = (unsigned short*)(ws);
    unsigned short* l0b  = (unsigned short*)(ws);
    float*          l1f  = (float*)(ws + 8388608);
    float*          scr  = (float*)(ws + 25165824);
    unsigned short* H1W  = (unsigned short*)(ws + 64000000);
    unsigned short* adjb = (unsigned short*)(ws + 80777216);
    unsigned short* w2b  = (unsigned short*)(ws + 80785408);
    float*          pre  = (float*)(ws + 80793600);
    unsigned short* W0b  = (unsigned short*)(ws + 147902464);
    unsigned short* W1b  = (unsigned short*)(ws + 155897856);
    unsigned short* W0hb = (unsigned short*)(ws + 156422144);   // 262,144 B
    unsigned short* W1hb = (unsigned short*)(ws + 156684288);   // 262,144 B

    const int n0e = in_sizes[6];    // 2*512*3904
    const int n1e = in_sizes[10];   // 2*512*256
    const int h0e = in_sizes[7];    // 2*512*128
    const int h1e = in_sizes[11];   // 2*512*128
    cvt_bf16_kernel<<<(n0e / 4 + 255) / 256, 256, 0, stream>>>(Wih0, W0b, n0e / 4);
    cvt_bf16_kernel<<<(n1e / 4 + 255) / 256, 256, 0, stream>>>(Wih1, W1b, n1e / 4);
    cvt_bf16_kernel<<<(h0e / 4 + 255) / 256, 256, 0, stream>>>(Whh0, W0hb, h0e / 4);
    cvt_bf16_kernel<<<(h1e / 4 + 255) / 256, 256, 0, stream>>>(Whh1, W1hb, h1e / 4);
    cvt_adj_kernel<<<16, 256, 0, stream>>>(adj, adjb);
    cvt_w2_kernel <<<16, 256, 0, stream>>>(Wg2, w2b);

    for (int ch = 0; ch < 2; ++ch) {
        int m_base = ch * CHUNK_M;
        for (int sc = 0; sc < CHUNK_M / SUB_M; ++sc) {
            gcn_h1_kernel<<<SUB_M, 256, 0, stream>>>(
                x, adj, Wg1, bg1, H1W, m_base + sc * SUB_M);
            gcn_mix_kernel<<<SUB_M / 2, 256, 0, stream>>>(
                H1W, adjb, w2b, bg2, seqb, sc * SUB_M);
        }
        gemm_mfma_kernel<<<dim3(CHUNK_M / 128, 8), 256, 0, stream>>>(
            seqb, W0b, bih0, bhh0, pre, NG_, m_base, M_TOT);
    }
    lstm_kernel<<<8, 512, 0, stream>>>(pre, W0hb, l0b);
    gemm_mfma_kernel<<<dim3(M_TOT / 128, 8), 256, 0, stream>>>(
        l0b, W1b, bih1, bhh1, pre, 256, 0, M_TOT);
    lstm_kernel<<<8, 512, 0, stream>>>(pre, W1hb, l1f);
    attn_scores_kernel<<<dim3(B_, 8), 256, 0, stream>>>(l1f, Wa1, ba1, Wa2, ba2, scr);
    attn_head_kernel<<<B_, 256, 0, stream>>>(l1f, scr, Wc1, bc1, Wc2, bc2, (float*)d_out);
}

// Round 15
// 1127.668 us; speedup vs baseline: 1.5493x; 1.3953x over previous
//
#include <hip/hip_runtime.h>
#include <math.h>

#define B_    64
#define T_    256
#define N_    61
#define FIN_  3
#define GH_   64
#define LH_   128
#define NC_   10
#define NG_   3904      /* N_*GH_ */
#define M_TOT 16384     /* B_*T_  */
#define CHUNK_M 8192
#define SUB_M   2048    /* GCN sub-chunk */

typedef __attribute__((ext_vector_type(8))) short bf16x8;
typedef __attribute__((ext_vector_type(4))) float f32x4;

__device__ __forceinline__ float gelu_exact(float x) {
    return 0.5f * x * (1.0f + erff(x * 0.70710678118654752f));
}
__device__ __forceinline__ float sigmoidf_(float x) {
    return 1.0f / (1.0f + expf(-x));
}
// fast HW transcendentals (LSTM gates only): v_exp_f32 + v_rcp_f32, ~1 ulp.
__device__ __forceinline__ float fsig(float x) {
    return __builtin_amdgcn_rcpf(1.f + __expf(-x));
}
__device__ __forceinline__ float ftanh(float x) {
    return 2.f * __builtin_amdgcn_rcpf(1.f + __expf(-2.f * x)) - 1.f;
}
__device__ __forceinline__ unsigned short f2bf(float f) {
    unsigned int u = __float_as_uint(f);
    u = (u + 0x7FFFu + ((u >> 16) & 1u)) >> 16;
    return (unsigned short)u;
}
__device__ __forceinline__ void store_h(float* p, float v) { *p = v; }
__device__ __forceinline__ void store_h(unsigned short* p, float v) { *p = f2bf(v); }

__device__ __forceinline__ void gload_lds16(const void* g, void* l) {
    __builtin_amdgcn_global_load_lds(
        (const __attribute__((address_space(1))) unsigned int*)g,
        (__attribute__((address_space(3))) unsigned int*)l,
        16, 0, 0);
}

// Shared 64-elem-row swizzle: XOR k with (row&3)*16. Used identically by every
// writer (global pre-swizzle) and reader (LDS frag read) — both-sides-or-neither.
__device__ __forceinline__ int swz(int row, int k) { return k ^ ((row & 3) << 4); }

// byte-level row swizzle for 256B bf16 rows (T2): same map on write and read.
__device__ __forceinline__ int hswz(int row, int byteoff) { return byteoff ^ ((row & 7) << 4); }

// ---------------------------------------------------------------------------
// fp32 -> bf16 weight conversion (4 elems/thread). n4 = ELEMENT count / 4.
// ---------------------------------------------------------------------------
__global__ __launch_bounds__(256) void cvt_bf16_kernel(
    const float* __restrict__ in, unsigned short* __restrict__ out, int n4)
{
    int i = blockIdx.x * 256 + threadIdx.x;
    if (i < n4) {
        float4 v = reinterpret_cast<const float4*>(in)[i];
        ushort4 o;
        o.x = f2bf(v.x); o.y = f2bf(v.y); o.z = f2bf(v.z); o.w = f2bf(v.w);
        reinterpret_cast<ushort4*>(out)[i] = o;
    }
}

// adj (61x61 fp32) -> adjb (64x64 bf16, zero-padded, pre-swizzled). grid 16.
__global__ __launch_bounds__(256) void cvt_adj_kernel(
    const float* __restrict__ adj, unsigned short* __restrict__ adjb)
{
    int i = blockIdx.x * 256 + threadIdx.x;
    if (i < 4096) {
        int n = i >> 6, m = i & 63;
        unsigned short v = (n < N_ && m < N_) ? f2bf(adj[n * N_ + m]) : (unsigned short)0;
        adjb[n * 64 + swz(n, m)] = v;
    }
}

// W2 (64x64 fp32) -> w2b (64x64 bf16, pre-swizzled). grid 16.
__global__ __launch_bounds__(256) void cvt_w2_kernel(
    const float* __restrict__ W2, unsigned short* __restrict__ w2b)
{
    int i = blockIdx.x * 256 + threadIdx.x;
    if (i < 4096) {
        int c = i >> 6, f = i & 63;
        w2b[c * 64 + swz(c, f)] = f2bf(W2[c * 64 + f]);
    }
}

// ---------------------------------------------------------------------------
// GCN K1: per (b,t): AX = A@X (fp32), H1 = gelu(AX @ W1^T + b1).
// Writes H1W bf16 TRANSPOSED [btl*64+c][m], m=61..63 zeroed, pre-swizzled.
// ---------------------------------------------------------------------------
__global__ __launch_bounds__(256) void gcn_h1_kernel(
    const float* __restrict__ x, const float* __restrict__ adj,
    const float* __restrict__ W1, const float* __restrict__ b1,
    unsigned short* __restrict__ H1W, int bt_base)
{
    __shared__ float adjs[N_ * 65];
    __shared__ float h1s [N_ * 65];
    __shared__ float xs [184];
    __shared__ float axs[184];
    __shared__ float w1s[192];
    __shared__ float b1s[64];

    const int tid = threadIdx.x;
    const int bt  = bt_base + blockIdx.x;

    for (int i = tid; i < N_ * N_; i += 256) {
        int n = i / 61, m = i - n * 61;
        adjs[n * 65 + m] = adj[i];
    }
    for (int i = tid; i < N_ * FIN_; i += 256) xs[i] = x[(size_t)bt * (N_ * FIN_) + i];
    for (int i = tid; i < GH_ * FIN_; i += 256) w1s[i] = W1[i];
    if (tid < GH_) b1s[tid] = b1[tid];
    __syncthreads();

    if (tid < N_ * FIN_) {
        int n = tid / 3, f = tid - n * 3;
        float acc = 0.f;
        for (int m = 0; m < N_; ++m) acc += adjs[n * 65 + m] * xs[m * 3 + f];
        axs[tid] = acc;
    }
    __syncthreads();

    for (int u = 0; u < 16; ++u) {
        int idx = tid + u * 256;
        if (idx < N_ * GH_) {
            int m = idx >> 6, c = idx & 63;
            float acc = b1s[c];
            acc += axs[m * 3 + 0] * w1s[c * 3 + 0];
            acc += axs[m * 3 + 1] * w1s[c * 3 + 1];
            acc += axs[m * 3 + 2] * w1s[c * 3 + 2];
            h1s[m * 65 + c] = gelu_exact(acc);
        }
    }
    __syncthreads();

    unsigned short* dst = H1W + (size_t)blockIdx.x * 4096;
    for (int i = tid; i < 4096; i += 256) {
        int c = i >> 6, m = i & 63;
        unsigned short v = (m < N_) ? f2bf(h1s[m * 65 + c]) : (unsigned short)0;
        dst[c * 64 + swz(c, m)] = v;
    }
}

// ---------------------------------------------------------------------------
// GCN K23: per block = 2 consecutive bt. MFMA both heavy stages.
// ---------------------------------------------------------------------------
__global__ __launch_bounds__(256) void gcn_mix_kernel(
    const unsigned short* __restrict__ H1W,
    const unsigned short* __restrict__ adjb,
    const unsigned short* __restrict__ w2b,
    const float* __restrict__ b2,
    unsigned short* __restrict__ seqc,
    int sc_base)
{
    __shared__ unsigned short adjbs[64 * 64];
    __shared__ unsigned short b1t [128 * 64];
    __shared__ unsigned short w2bs[64 * 64];
    __shared__ unsigned short T   [128 * 64];
    __shared__ float b2s[64];

    const int tid = threadIdx.x;
    const int w   = tid >> 6;
    const int l   = tid & 63;
    const int lr  = l & 15, lk = l >> 4;
    const int p   = blockIdx.x;

    #pragma unroll
    for (int q = 0; q < 2; ++q)
        gload_lds16(adjb + q * 2048 + w * 512 + l * 8, &adjbs[q * 2048 + w * 512]);
    #pragma unroll
    for (int q = 0; q < 2; ++q)
        gload_lds16(w2b + q * 2048 + w * 512 + l * 8, &w2bs[q * 2048 + w * 512]);
    #pragma unroll
    for (int q = 0; q < 4; ++q)
        gload_lds16(H1W + (size_t)p * 8192 + q * 2048 + w * 512 + l * 8,
                    &b1t[q * 2048 + w * 512]);
    if (tid < 64) b2s[tid] = b2[tid];
    __syncthreads();

    f32x4 acc1[4][2];
    #pragma unroll
    for (int i = 0; i < 4; ++i)
        #pragma unroll
        for (int j = 0; j < 2; ++j) acc1[i][j] = (f32x4){0.f, 0.f, 0.f, 0.f};

    #pragma unroll
    for (int kk = 0; kk < 2; ++kk) {
        const int kb = kk * 32 + lk * 8;
        bf16x8 af[4], bfr[2];
        #pragma unroll
        for (int i = 0; i < 4; ++i) {
            int rn = i * 16 + lr;
            af[i] = *reinterpret_cast<const bf16x8*>(&adjbs[rn * 64 + swz(rn, kb)]);
        }
        #pragma unroll
        for (int j = 0; j < 2; ++j) {
            int rb = w * 32 + j * 16 + lr;
            bfr[j] = *reinterpret_cast<const bf16x8*>(&b1t[rb * 64 + swz(rb, kb)]);
        }
        #pragma unroll
        for (int i = 0; i < 4; ++i)
            #pragma unroll
            for (int j = 0; j < 2; ++j)
                acc1[i][j] = __builtin_amdgcn_mfma_f32_16x16x32_bf16(af[i], bfr[j], acc1[i][j], 0, 0, 0);
    }

    #pragma unroll
    for (int i = 0; i < 4; ++i) {
        #pragma unroll
        for (int j = 0; j < 2; ++j) {
            int col = w * 32 + j * 16 + lr;
            int c   = col & 63;
            int rbase = (col >> 6) * 64;
            #pragma unroll
            for (int r = 0; r < 4; ++r) {
                int n   = i * 16 + lk * 4 + r;
                int row = rbase + n;
                T[row * 64 + swz(row, c)] = f2bf(acc1[i][j][r]);
            }
        }
    }
    __syncthreads();

    f32x4 acc2[2][4];
    #pragma unroll
    for (int i = 0; i < 2; ++i)
        #pragma unroll
        for (int j = 0; j < 4; ++j) acc2[i][j] = (f32x4){0.f, 0.f, 0.f, 0.f};

    #pragma unroll
    for (int kk = 0; kk < 2; ++kk) {
        const int kb = kk * 32 + lk * 8;
        bf16x8 a2[2], bw[4];
        #pragma unroll
        for (int i = 0; i < 2; ++i) {
            int r2 = w * 32 + i * 16 + lr;
            a2[i] = *reinterpret_cast<const bf16x8*>(&T[r2 * 64 + swz(r2, kb)]);
        }
        #pragma unroll
        for (int j = 0; j < 4; ++j) {
            int co = j * 16 + lr;
            bw[j] = *reinterpret_cast<const bf16x8*>(&w2bs[co * 64 + swz(co, kb)]);
        }
        #pragma unroll
        for (int i = 0; i < 2; ++i)
            #pragma unroll
            for (int j = 0; j < 4; ++j)
                acc2[i][j] = __builtin_amdgcn_mfma_f32_16x16x32_bf16(a2[i], bw[j], acc2[i][j], 0, 0, 0);
    }

    #pragma unroll
    for (int i = 0; i < 2; ++i) {
        #pragma unroll
        for (int j = 0; j < 4; ++j) {
            int co = j * 16 + lr;
            float bias = b2s[co];
            #pragma unroll
            for (int r = 0; r < 4; ++r) {
                int row = w * 32 + i * 16 + lk * 4 + r;
                int n   = row & 63;
                if (n < N_) {
                    int btc = sc_base + p * 2 + (row >> 6);
                    seqc[(size_t)btc * NG_ + n * 64 + co] =
                        f2bf(gelu_exact(acc2[i][j][r] + bias));
                }
            }
        }
    }
}

// ---------------------------------------------------------------------------
// bf16 MFMA GEMM: C = A(Mc x K) @ W(1024 x K)^T + bias_a + bias_b
// ---------------------------------------------------------------------------
__global__ __launch_bounds__(256) void gemm_mfma_kernel(
    const unsigned short* __restrict__ A, const unsigned short* __restrict__ W,
    const float* __restrict__ bias_a, const float* __restrict__ bias_b,
    float* __restrict__ Cout, int K, int m_base, int Mtot)
{
    __shared__ unsigned short As[128 * 32];
    __shared__ unsigned short Bs[128 * 32];

    const int tid = threadIdx.x;
    const int w   = tid >> 6;
    const int l   = tid & 63;
    const int wr  = w >> 1, wc = w & 1;
    const int lr  = l & 15, lk = l >> 4;

    const int m0 = blockIdx.x * 128;
    const int n0 = blockIdx.y * 128;

    f32x4 acc[4][4];
    #pragma unroll
    for (int i = 0; i < 4; ++i)
        #pragma unroll
        for (int j = 0; j < 4; ++j) acc[i][j] = (f32x4){0.f, 0.f, 0.f, 0.f};

    const int row_a0 = tid >> 2;
    const int cb     = (tid & 3) * 8;
    const unsigned short* aptr0 = A + (size_t)(m0 + row_a0) * K + cb;
    const unsigned short* aptr1 = A + (size_t)(m0 + row_a0 + 64) * K + cb;
    const unsigned short* bptr0 = W + (size_t)(n0 + row_a0) * K + cb;
    const unsigned short* bptr1 = W + (size_t)(n0 + row_a0 + 64) * K + cb;
    unsigned short* lA0 = &As[w * 512];
    unsigned short* lA1 = &As[2048 + w * 512];
    unsigned short* lB0 = &Bs[w * 512];
    unsigned short* lB1 = &Bs[2048 + w * 512];

    for (int k0 = 0; k0 < K; k0 += 32) {
        gload_lds16(aptr0 + k0, lA0);
        gload_lds16(aptr1 + k0, lA1);
        gload_lds16(bptr0 + k0, lB0);
        gload_lds16(bptr1 + k0, lB1);
        __syncthreads();

        bf16x8 af[4], bfr[4];
        #pragma unroll
        for (int i = 0; i < 4; ++i)
            af[i] = *reinterpret_cast<const bf16x8*>(&As[(wr * 64 + i * 16 + lr) * 32 + lk * 8]);
        #pragma unroll
        for (int j = 0; j < 4; ++j)
            bfr[j] = *reinterpret_cast<const bf16x8*>(&Bs[(wc * 64 + j * 16 + lr) * 32 + lk * 8]);
        #pragma unroll
        for (int i = 0; i < 4; ++i)
            #pragma unroll
            for (int j = 0; j < 4; ++j)
                acc[i][j] = __builtin_amdgcn_mfma_f32_16x16x32_bf16(af[i], bfr[j], acc[i][j], 0, 0, 0);
        __syncthreads();
    }

    #pragma unroll
    for (int i = 0; i < 4; ++i) {
        #pragma unroll
        for (int j = 0; j < 4; ++j) {
            int n = n0 + wc * 64 + j * 16 + lr;
            float ba = bias_a[n] + bias_b[n];
            int d = n >> 9, g = n & 511;
            #pragma unroll
            for (int r = 0; r < 4; ++r) {
                int m = m_base + m0 + wr * 64 + i * 16 + lk * 4 + r;
                Cout[((size_t)d * Mtot + m) * 512 + g] = acc[i][j][r] + ba;
            }
        }
    }
}

// ---------------------------------------------------------------------------
// MFMA-batched BiLSTM recurrence, pipelined (r14) + FAST GATE TRANSCENDENTALS.
// r14 counters (normalized to the 8 active CUs): VALU ~79%, Mfma ~10% -> the
// bottleneck is the 4-cells/lane gate math with precise expf/tanhf. Replace
// with v_exp_f32 + v_rcp_f32 forms (fsig/ftanh, ~1 ulp): ~10x fewer VALU ops
// on the only serial resource. Datapath/layout/barriers identical to r14.
// ---------------------------------------------------------------------------
#define LSTM_STEP(S, PUSE)                                                          \
    {                                                                               \
        const int t_ = d ? (T_ - 1 - (S)) : (S);                                    \
        const char* hb_ = (const char*)&hbuf[cur][0];                               \
        const int rowb_ = lr * 256;                                                 \
        const int xo_   = (lr & 7) << 4;                                            \
        bf16x8 a0 = *reinterpret_cast<const bf16x8*>(hb_ + rowb_ + ((0 * 64 + lk * 16) ^ xo_)); \
        bf16x8 a1 = *reinterpret_cast<const bf16x8*>(hb_ + rowb_ + ((1 * 64 + lk * 16) ^ xo_)); \
        bf16x8 a2 = *reinterpret_cast<const bf16x8*>(hb_ + rowb_ + ((2 * 64 + lk * 16) ^ xo_)); \
        bf16x8 a3 = *reinterpret_cast<const bf16x8*>(hb_ + rowb_ + ((3 * 64 + lk * 16) ^ xo_)); \
        f32x4 acc_[4];                                                              \
        _Pragma("unroll")                                                           \
        for (int g_ = 0; g_ < 4; ++g_) acc_[g_] = PUSE[g_];                         \
        if ((S) + 2 < T_) {                                                         \
            int tn_ = d ? (T_ - 3 - (S)) : ((S) + 2);                               \
            _Pragma("unroll")                                                       \
            for (int g_ = 0; g_ < 4; ++g_)                                          \
                _Pragma("unroll")                                                   \
                for (int r_ = 0; r_ < 4; ++r_)                                      \
                    PUSE[g_][r_] = pb[((size_t)(lk * 4 + r_) * T_ + tn_) * 512 + g_ * 128]; \
        }                                                                           \
        _Pragma("unroll")                                                           \
        for (int g_ = 0; g_ < 4; ++g_) {                                            \
            acc_[g_] = __builtin_amdgcn_mfma_f32_16x16x32_bf16(a0, bw[g_][0], acc_[g_], 0, 0, 0); \
            acc_[g_] = __builtin_amdgcn_mfma_f32_16x16x32_bf16(a1, bw[g_][1], acc_[g_], 0, 0, 0); \
            acc_[g_] = __builtin_amdgcn_mfma_f32_16x16x32_bf16(a2, bw[g_][2], acc_[g_], 0, 0, 0); \
            acc_[g_] = __builtin_amdgcn_mfma_f32_16x16x32_bf16(a3, bw[g_][3], acc_[g_], 0, 0, 0); \
        }                                                                           \
        char* hn_ = (char*)&hbuf[cur ^ 1][0];                                       \
        _Pragma("unroll")                                                           \
        for (int r_ = 0; r_ < 4; ++r_) {                                            \
            float gi_ = acc_[0][r_], gf_ = acc_[1][r_];                             \
            float gv_ = acc_[2][r_], go_ = acc_[3][r_];                             \
            cst[r_] = fsig(gf_) * cst[r_] + fsig(gi_) * ftanh(gv_);                 \
            float h_ = fsig(go_) * ftanh(cst[r_]);                                  \
            int m_ = lk * 4 + r_;                                                   \
            *(unsigned short*)(hn_ + m_ * 256 + hswz(m_, unit * 2)) = f2bf(h_);     \
            store_h(&hout[((size_t)(bg * 16 + m_) * T_ + t_) * 256 + d * 128 + unit], h_); \
        }                                                                           \
        asm volatile("s_waitcnt lgkmcnt(0)" ::: "memory");                          \
        __builtin_amdgcn_s_barrier();                                               \
        __builtin_amdgcn_sched_barrier(0);                                          \
        cur ^= 1;                                                                   \
    }

template <typename OT>
__global__ __launch_bounds__(512) void lstm_kernel(
    const float* __restrict__ pre,           // [d][b][t][512]
    const unsigned short* __restrict__ Whb,  // [2][512][128] bf16
    OT* __restrict__ hout)                   // [b][t][256]
{
    const int d   = blockIdx.x >> 2;
    const int bg  = blockIdx.x & 3;
    const int tid = threadIdx.x;
    const int w   = tid >> 6;
    const int l   = tid & 63;
    const int lr  = l & 15;
    const int lk  = l >> 4;
    const int unit = w * 16 + lr;

    // B fragments: Whh[d][gate*128 + unit][kt*32 + lk*8 ..+7], 16 x bf16x8.
    bf16x8 bw[4][4];
    #pragma unroll
    for (int g = 0; g < 4; ++g)
        #pragma unroll
        for (int kt = 0; kt < 4; ++kt)
            bw[g][kt] = *reinterpret_cast<const bf16x8*>(
                Whb + ((size_t)d * 512 + g * 128 + unit) * 128 + kt * 32 + lk * 8);

    __shared__ unsigned short hbuf[2][16 * 128];   // [batch row=256B][unit], swizzled
    for (int i = tid; i < 1024; i += 512)
        reinterpret_cast<unsigned int*>(&hbuf[0][0])[i] = 0u;

    float cst[4] = {0.f, 0.f, 0.f, 0.f};

    // per-lane pre base: batch m = lk*4+r, gate g:
    // pre[((d*64 + bg*16 + m)*T + t)*512 + g*128 + unit]
    const float* pb = pre + ((size_t)(d * B_ + bg * 16) * T_) * 512 + unit;

    f32x4 pE[4], pO[4];
    {   // prologue loads for t(0), t(1)
        int t0 = d ? (T_ - 1) : 0;
        int t1 = d ? (T_ - 2) : 1;
        #pragma unroll
        for (int g = 0; g < 4; ++g)
            #pragma unroll
            for (int r = 0; r < 4; ++r) {
                pE[g][r] = pb[((size_t)(lk * 4 + r) * T_ + t0) * 512 + g * 128];
                pO[g][r] = pb[((size_t)(lk * 4 + r) * T_ + t1) * 512 + g * 128];
            }
    }
    __syncthreads();   // h[0] zeros visible (one-time full drain: acceptable)

    int cur = 0;
    for (int s = 0; s < T_; s += 2) {
        LSTM_STEP(s,     pE);
        LSTM_STEP(s + 1, pO);
    }
}

// ---------------------------------------------------------------------------
// attention scores: block per (b, 32-t tile). Rows staged in LDS once.
// ---------------------------------------------------------------------------
__global__ __launch_bounds__(256) void attn_scores_kernel(
    const float* __restrict__ l1, const float* __restrict__ Wa1,
    const float* __restrict__ ba1, const float* __restrict__ Wa2,
    const float* __restrict__ ba2, float* __restrict__ scores)
{
    const int b   = blockIdx.x;
    const int t0  = blockIdx.y * 32;
    const int tid = threadIdx.x;
    const int j   = tid & 63, kq = tid >> 6;

    float w[64];
    const float* wsrc = Wa1 + j * 256 + kq * 64;
    #pragma unroll
    for (int k = 0; k < 64; ++k) w[k] = wsrc[k];

    __shared__ __align__(16) float rows[32 * 256];
    __shared__ float part[256];

    const float4* src = reinterpret_cast<const float4*>(
        l1 + (size_t)b * T_ * 256 + (size_t)t0 * 256);
    float4* dstv = reinterpret_cast<float4*>(rows);
    #pragma unroll
    for (int q = 0; q < 8; ++q) dstv[q * 256 + tid] = src[q * 256 + tid];

    float wa2 = (tid < 64) ? Wa2[tid] : 0.f;
    float bj  = (tid < 64) ? ba1[tid] : 0.f;
    float bb2 = ba2[0];
    __syncthreads();

    for (int tl = 0; tl < 32; ++tl) {
        const float* row = &rows[tl * 256 + kq * 64];
        float acc = 0.f;
        #pragma unroll
        for (int k4 = 0; k4 < 16; ++k4) {
            float4 hv = *reinterpret_cast<const float4*>(&row[k4 * 4]);
            acc += w[k4 * 4 + 0] * hv.x + w[k4 * 4 + 1] * hv.y
                 + w[k4 * 4 + 2] * hv.z + w[k4 * 4 + 3] * hv.w;
        }
        part[tid] = acc;
        __syncthreads();
        if (tid < 64) {
            float dj = part[tid] + part[tid + 64] + part[tid + 128] + part[tid + 192];
            float sv = tanhf(dj + bj) * wa2;
            #pragma unroll
            for (int off = 32; off > 0; off >>= 1) sv += __shfl_xor(sv, off);
            if (tid == 0) scores[b * T_ + t0 + tl] = sv + bb2;
        }
        __syncthreads();
    }
}

// ---------------------------------------------------------------------------
// softmax + context + classifier head: block per b.
// ---------------------------------------------------------------------------
__global__ __launch_bounds__(256) void attn_head_kernel(
    const float* __restrict__ l1, const float* __restrict__ scores,
    const float* __restrict__ Wc1, const float* __restrict__ bc1,
    const float* __restrict__ Wc2, const float* __restrict__ bc2,
    float* __restrict__ out)
{
    const int b   = blockIdx.x;
    const int tid = threadIdx.x;
    __shared__ float wsl[256];
    __shared__ float red[8];
    __shared__ float ctx[256];
    __shared__ float hid[128];
    __shared__ float wc1s[128 * 65];

    float v = scores[b * T_ + tid];
    float mx = v;
    #pragma unroll
    for (int off = 32; off > 0; off >>= 1) mx = fmaxf(mx, __shfl_xor(mx, off));
    if ((tid & 63) == 0) red[tid >> 6] = mx;
    __syncthreads();
    mx = fmaxf(fmaxf(red[0], red[1]), fmaxf(red[2], red[3]));
    float e = expf(v - mx);
    float s = e;
    #pragma unroll
    for (int off = 32; off > 0; off >>= 1) s += __shfl_xor(s, off);
    if ((tid & 63) == 0) red[4 + (tid >> 6)] = s;
    __syncthreads();
    float denom = red[4] + red[5] + red[6] + red[7];
    wsl[tid] = e / denom;
    __syncthreads();

    float acc = 0.f;
    const float* lb = l1 + (size_t)b * T_ * 256 + tid;
    #pragma unroll 4
    for (int t = 0; t < T_; ++t) acc += lb[(size_t)t * 256] * wsl[t];
    ctx[tid] = acc;
    __syncthreads();

    float hacc = (tid < 128) ? bc1[tid] : 0.f;
    for (int kb = 0; kb < 4; ++kb) {
        for (int i = tid; i < 128 * 64; i += 256) {
            int jj = i >> 6, kk = i & 63;
            wc1s[jj * 65 + kk] = Wc1[jj * 256 + kb * 64 + kk];
        }
        __syncthreads();
        if (tid < 128) {
            #pragma unroll
            for (int kk = 0; kk < 64; ++kk)
                hacc += ctx[kb * 64 + kk] * wc1s[tid * 65 + kk];
        }
        __syncthreads();
    }
    if (tid < 128) hid[tid] = fmaxf(hacc, 0.f);
    __syncthreads();

    if (tid < NC_) {
        float a = bc2[tid];
        #pragma unroll
        for (int k = 0; k < 128; ++k) a += hid[k] * Wc2[tid * 128 + k];
        out[b * NC_ + tid] = a;
    }
}

// ---------------------------------------------------------------------------
extern "C" void kernel_launch(void* const* d_in, const int* in_sizes, int n_in,
                              void* d_out, int out_size, void* d_ws, size_t ws_size,
                              hipStream_t stream)
{
    const float* x    = (const float*)d_in[0];
    const float* adj  = (const float*)d_in[1];
    const float* Wg1  = (const float*)d_in[2];
    const float* bg1  = (const float*)d_in[3];
    const float* Wg2  = (const float*)d_in[4];
    const float* bg2  = (const float*)d_in[5];
    const float* Wih0 = (const float*)d_in[6];
    const float* Whh0 = (const float*)d_in[7];
    const float* bih0 = (const float*)d_in[8];
    const float* bhh0 = (const float*)d_in[9];
    const float* Wih1 = (const float*)d_in[10];
    const float* Whh1 = (const float*)d_in[11];
    const float* bih1 = (const float*)d_in[12];
    const float* bhh1 = (const float*)d_in[13];
    const float* Wa1  = (const float*)d_in[14];
    const float* ba1  = (const float*)d_in[15];
    const float* Wa2  = (const float*)d_in[16];
    const float* ba2  = (const float*)d_in[17];
    const float* Wc1  = (const float*)d_in[18];
    const float* bc1  = (const float*)d_in[19];
    const float* Wc2  = (const float*)d_in[20];
    const float* bc2  = (const float*)d_in[21];

    char* ws = (char*)d_ws;
    // Workspace (bytes). Peak 156,946,432 < 160,432,128 proven by round-1 pass.
    unsigned short* seqb = (unsigned short*)(ws);
    unsigned short* l0b  = (unsigned short*)(ws);
    float*          l1f  = (float*)(ws + 8388608);
    float*          scr  = (float*)(ws + 25165824);
    unsigned short* H1W  = (unsigned short*)(ws + 64000000);
    unsigned short* adjb = (unsigned short*)(ws + 80777216);
    unsigned short* w2b  = (unsigned short*)(ws + 80785408);
    float*          pre  = (float*)(ws + 80793600);
    unsigned short* W0b  = (unsigned short*)(ws + 147902464);
    unsigned short* W1b  = (unsigned short*)(ws + 155897856);
    unsigned short* W0hb = (unsigned short*)(ws + 156422144);   // 262,144 B
    unsigned short* W1hb = (unsigned short*)(ws + 156684288);   // 262,144 B

    const int n0e = in_sizes[6];    // 2*512*3904
    const int n1e = in_sizes[10];   // 2*512*256
    const int h0e = in_sizes[7];    // 2*512*128
    const int h1e = in_sizes[11];   // 2*512*128
    cvt_bf16_kernel<<<(n0e / 4 + 255) / 256, 256, 0, stream>>>(Wih0, W0b, n0e / 4);
    cvt_bf16_kernel<<<(n1e / 4 + 255) / 256, 256, 0, stream>>>(Wih1, W1b, n1e / 4);
    cvt_bf16_kernel<<<(h0e / 4 + 255) / 256, 256, 0, stream>>>(Whh0, W0hb, h0e / 4);
    cvt_bf16_kernel<<<(h1e / 4 + 255) / 256, 256, 0, stream>>>(Whh1, W1hb, h1e / 4);
    cvt_adj_kernel<<<16, 256, 0, stream>>>(adj, adjb);
    cvt_w2_kernel <<<16, 256, 0, stream>>>(Wg2, w2b);

    for (int ch = 0; ch < 2; ++ch) {
        int m_base = ch * CHUNK_M;
        for (int sc = 0; sc < CHUNK_M / SUB_M; ++sc) {
            gcn_h1_kernel<<<SUB_M, 256, 0, stream>>>(
                x, adj, Wg1, bg1, H1W, m_base + sc * SUB_M);
            gcn_mix_kernel<<<SUB_M / 2, 256, 0, stream>>>(
                H1W, adjb, w2b, bg2, seqb, sc * SUB_M);
        }
        gemm_mfma_kernel<<<dim3(CHUNK_M / 128, 8), 256, 0, stream>>>(
            seqb, W0b, bih0, bhh0, pre, NG_, m_base, M_TOT);
    }
    lstm_kernel<<<8, 512, 0, stream>>>(pre, W0hb, l0b);
    gemm_mfma_kernel<<<dim3(M_TOT / 128, 8), 256, 0, stream>>>(
        l0b, W1b, bih1, bhh1, pre, 256, 0, M_TOT);
    lstm_kernel<<<8, 512, 0, stream>>>(pre, W1hb, l1f);
    attn_scores_kernel<<<dim3(B_, 8), 256, 0, stream>>>(l1f, Wa1, ba1, Wa2, ba2, scr);
    attn_head_kernel<<<B_, 256, 0, stream>>>(l1f, scr, Wc1, bc1, Wc2, bc2, (float*)d_out);
}

// Round 16
// 1018.708 us; speedup vs baseline: 1.7150x; 1.1070x over previous
//
#include <hip/hip_runtime.h>
#include <math.h>

#define B_    64
#define T_    256
#define N_    61
#define FIN_  3
#define GH_   64
#define LH_   128
#define NC_   10
#define NG_   3904      /* N_*GH_ */
#define M_TOT 16384     /* B_*T_  */
#define CHUNK_M 8192

typedef __attribute__((ext_vector_type(8))) short bf16x8;
typedef __attribute__((ext_vector_type(4))) float f32x4;

__device__ __forceinline__ float gelu_exact(float x) {
    return 0.5f * x * (1.0f + erff(x * 0.70710678118654752f));
}
__device__ __forceinline__ float sigmoidf_(float x) {
    return 1.0f / (1.0f + expf(-x));
}
// fast HW transcendentals (LSTM gates only): v_exp_f32 + v_rcp_f32, ~1 ulp.
__device__ __forceinline__ float fsig(float x) {
    return __builtin_amdgcn_rcpf(1.f + __expf(-x));
}
__device__ __forceinline__ float ftanh(float x) {
    return 2.f * __builtin_amdgcn_rcpf(1.f + __expf(-2.f * x)) - 1.f;
}
__device__ __forceinline__ unsigned short f2bf(float f) {
    unsigned int u = __float_as_uint(f);
    u = (u + 0x7FFFu + ((u >> 16) & 1u)) >> 16;
    return (unsigned short)u;
}
__device__ __forceinline__ void store_h(float* p, float v) { *p = v; }
__device__ __forceinline__ void store_h(unsigned short* p, float v) { *p = f2bf(v); }

__device__ __forceinline__ void gload_lds16(const void* g, void* l) {
    __builtin_amdgcn_global_load_lds(
        (const __attribute__((address_space(1))) unsigned int*)g,
        (__attribute__((address_space(3))) unsigned int*)l,
        16, 0, 0);
}

// Shared 64-elem-row swizzle: XOR k with (row&3)*16. Used identically by every
// writer (global pre-swizzle / LDS write) and reader — both-sides-or-neither.
__device__ __forceinline__ int swz(int row, int k) { return k ^ ((row & 3) << 4); }

// byte-level row swizzle for 256B bf16 rows (T2): same map on write and read.
__device__ __forceinline__ int hswz(int row, int byteoff) { return byteoff ^ ((row & 7) << 4); }

// ---------------------------------------------------------------------------
// fp32 -> bf16 weight conversion (4 elems/thread). n4 = ELEMENT count / 4.
// ---------------------------------------------------------------------------
__global__ __launch_bounds__(256) void cvt_bf16_kernel(
    const float* __restrict__ in, unsigned short* __restrict__ out, int n4)
{
    int i = blockIdx.x * 256 + threadIdx.x;
    if (i < n4) {
        float4 v = reinterpret_cast<const float4*>(in)[i];
        ushort4 o;
        o.x = f2bf(v.x); o.y = f2bf(v.y); o.z = f2bf(v.z); o.w = f2bf(v.w);
        reinterpret_cast<ushort4*>(out)[i] = o;
    }
}

// adj (61x61 fp32) -> adjb (64x64 bf16, zero-padded, pre-swizzled). grid 16.
__global__ __launch_bounds__(256) void cvt_adj_kernel(
    const float* __restrict__ adj, unsigned short* __restrict__ adjb)
{
    int i = blockIdx.x * 256 + threadIdx.x;
    if (i < 4096) {
        int n = i >> 6, m = i & 63;
        unsigned short v = (n < N_ && m < N_) ? f2bf(adj[n * N_ + m]) : (unsigned short)0;
        adjb[n * 64 + swz(n, m)] = v;
    }
}

// W2 (64x64 fp32) -> w2b (64x64 bf16, pre-swizzled). grid 16.
__global__ __launch_bounds__(256) void cvt_w2_kernel(
    const float* __restrict__ W2, unsigned short* __restrict__ w2b)
{
    int i = blockIdx.x * 256 + threadIdx.x;
    if (i < 4096) {
        int c = i >> 6, f = i & 63;
        w2b[c * 64 + swz(c, f)] = f2bf(W2[c * 64 + f]);
    }
}

// ---------------------------------------------------------------------------
// FUSED GCN: one kernel per chunk (grid = CHUNK_M/2, block = 2 consecutive bt).
// Replaces gcn_h1 (per-bt, H1 -> 16.7MB global round-trip) + gcn_mix.
//   A) stage adj fp32 / x / W1 / biases; gload adjb,w2b; zero b1t
//   B) AX = A@X (fp32, rank-3)
//   C) H1 = gelu(AX@W1^T+b1) -> b1t bf16 transposed [btl*64+c][swz(c,m)]
//   D) stage1 MFMA: AH1 = adjb @ b1t-tile^T -> bounce to T (swizzled)
//   E) stage2 MFMA: seq = gelu(T @ w2b^T + b2)
// LDS 53.4KB (adjs fp32 UNIONed with T — disjoint phases, barrier-separated);
// 3 blocks/CU. Saves ~270MB H1W HBM traffic + 14 launches per run.
// ---------------------------------------------------------------------------
__global__ __launch_bounds__(256) void gcn_fused_kernel(
    const float* __restrict__ x, const float* __restrict__ adj,
    const float* __restrict__ W1, const float* __restrict__ b1,
    const unsigned short* __restrict__ adjb,   // [64][64] pre-swizzled bf16
    const unsigned short* __restrict__ w2b,    // [64][64] pre-swizzled bf16
    const float* __restrict__ b2,
    unsigned short* __restrict__ seqc,         // chunk-local [CHUNK_M][3904]
    int m_base)
{
    __shared__ __align__(16) char ldsbuf[53376];
    float*          adjs  = (float*)(ldsbuf);                    // phases A-B (61x65 f32)
    unsigned short* T     = (unsigned short*)(ldsbuf);           // phases D-E (union)
    unsigned short* b1t   = (unsigned short*)(ldsbuf + 16384);   // 128x64 bf16
    unsigned short* adjbs = (unsigned short*)(ldsbuf + 32768);   // 8KB
    unsigned short* w2bs  = (unsigned short*)(ldsbuf + 40960);   // 8KB
    float*          xs2   = (float*)(ldsbuf + 49152);            // 2x184
    float*          axs2  = (float*)(ldsbuf + 50624);            // 2x184
    float*          w1s   = (float*)(ldsbuf + 52096);            // 192
    float*          b1s   = (float*)(ldsbuf + 52864);            // 64
    float*          b2s   = (float*)(ldsbuf + 53120);            // 64

    const int tid = threadIdx.x;
    const int w   = tid >> 6;
    const int l   = tid & 63;
    const int lr  = l & 15, lk = l >> 4;
    const int p   = blockIdx.x;               // bt pair within chunk
    const int bt0 = m_base + p * 2;           // global bt of first

    // ---- A: staging
    #pragma unroll
    for (int q = 0; q < 2; ++q)
        gload_lds16(adjb + q * 2048 + w * 512 + l * 8, adjbs + q * 2048 + w * 512);
    #pragma unroll
    for (int q = 0; q < 2; ++q)
        gload_lds16(w2b + q * 2048 + w * 512 + l * 8, w2bs + q * 2048 + w * 512);
    for (int i = tid; i < N_ * N_; i += 256) {
        int n = i / 61, m = i - n * 61;
        adjs[n * 65 + m] = adj[i];
    }
    for (int i = tid; i < 2 * 183; i += 256) {
        int btl = i / 183, r = i - btl * 183;
        xs2[btl * 184 + r] = x[(size_t)(bt0 + btl) * 183 + r];
    }
    if (tid < 192) w1s[tid] = W1[tid];
    if (tid < 64) { b1s[tid] = b1[tid]; b2s[tid] = b2[tid]; }
    for (int i = tid; i < 4096; i += 256)          // zero b1t (pads m=61..63)
        reinterpret_cast<unsigned int*>(b1t)[i] = 0u;
    __syncthreads();

    // ---- B: AX (2 x 61x3), fp32
    if (tid < 366) {
        int btl = tid / 183, idx = tid - btl * 183;
        int n = idx / 3, f = idx - n * 3;
        float acc = 0.f;
        for (int m = 0; m < N_; ++m) acc += adjs[n * 65 + m] * xs2[btl * 184 + m * 3 + f];
        axs2[btl * 184 + idx] = acc;
    }
    __syncthreads();

    // ---- C: H1 = gelu(AX @ W1^T + b1) -> b1t bf16, transposed + swizzled
    for (int u = 0; u < 31; ++u) {
        int idx = tid + u * 256;
        if (idx < 2 * N_ * GH_) {
            int btl = idx / NG_;
            int r   = idx - btl * NG_;
            int m = r >> 6, c = r & 63;
            float acc = b1s[c];
            acc += axs2[btl * 184 + m * 3 + 0] * w1s[c * 3 + 0];
            acc += axs2[btl * 184 + m * 3 + 1] * w1s[c * 3 + 1];
            acc += axs2[btl * 184 + m * 3 + 2] * w1s[c * 3 + 2];
            b1t[(btl * 64 + c) * 64 + swz(c, m)] = f2bf(gelu_exact(acc));
        }
    }
    __syncthreads();   // adjs dead from here; T (union) may be written

    // ---- D: stage1 MFMA: AH1[n][col], wave w owns cols w*32..w*32+31
    f32x4 acc1[4][2];
    #pragma unroll
    for (int i = 0; i < 4; ++i)
        #pragma unroll
        for (int j = 0; j < 2; ++j) acc1[i][j] = (f32x4){0.f, 0.f, 0.f, 0.f};

    #pragma unroll
    for (int kk = 0; kk < 2; ++kk) {
        const int kb = kk * 32 + lk * 8;
        bf16x8 af[4], bfr[2];
        #pragma unroll
        for (int i = 0; i < 4; ++i) {
            int rn = i * 16 + lr;
            af[i] = *reinterpret_cast<const bf16x8*>(&adjbs[rn * 64 + swz(rn, kb)]);
        }
        #pragma unroll
        for (int j = 0; j < 2; ++j) {
            int rb = w * 32 + j * 16 + lr;
            bfr[j] = *reinterpret_cast<const bf16x8*>(&b1t[rb * 64 + swz(rb, kb)]);
        }
        #pragma unroll
        for (int i = 0; i < 4; ++i)
            #pragma unroll
            for (int j = 0; j < 2; ++j)
                acc1[i][j] = __builtin_amdgcn_mfma_f32_16x16x32_bf16(af[i], bfr[j], acc1[i][j], 0, 0, 0);
    }

    // bounce: AH1[n][col] -> T[(col>>6)*64 + n][col&63], bf16, swizzled
    #pragma unroll
    for (int i = 0; i < 4; ++i) {
        #pragma unroll
        for (int j = 0; j < 2; ++j) {
            int col = w * 32 + j * 16 + lr;
            int c   = col & 63;
            int rbase = (col >> 6) * 64;
            #pragma unroll
            for (int r = 0; r < 4; ++r) {
                int n   = i * 16 + lk * 4 + r;
                int row = rbase + n;
                T[row * 64 + swz(row, c)] = f2bf(acc1[i][j][r]);
            }
        }
    }
    __syncthreads();

    // ---- E: stage2 MFMA: seq = gelu(T @ w2b^T + b2)
    f32x4 acc2[2][4];
    #pragma unroll
    for (int i = 0; i < 2; ++i)
        #pragma unroll
        for (int j = 0; j < 4; ++j) acc2[i][j] = (f32x4){0.f, 0.f, 0.f, 0.f};

    #pragma unroll
    for (int kk = 0; kk < 2; ++kk) {
        const int kb = kk * 32 + lk * 8;
        bf16x8 a2[2], bwv[4];
        #pragma unroll
        for (int i = 0; i < 2; ++i) {
            int r2 = w * 32 + i * 16 + lr;
            a2[i] = *reinterpret_cast<const bf16x8*>(&T[r2 * 64 + swz(r2, kb)]);
        }
        #pragma unroll
        for (int j = 0; j < 4; ++j) {
            int co = j * 16 + lr;
            bwv[j] = *reinterpret_cast<const bf16x8*>(&w2bs[co * 64 + swz(co, kb)]);
        }
        #pragma unroll
        for (int i = 0; i < 2; ++i)
            #pragma unroll
            for (int j = 0; j < 4; ++j)
                acc2[i][j] = __builtin_amdgcn_mfma_f32_16x16x32_bf16(a2[i], bwv[j], acc2[i][j], 0, 0, 0);
    }

    #pragma unroll
    for (int i = 0; i < 2; ++i) {
        #pragma unroll
        for (int j = 0; j < 4; ++j) {
            int co = j * 16 + lr;
            float bias = b2s[co];
            #pragma unroll
            for (int r = 0; r < 4; ++r) {
                int row = w * 32 + i * 16 + lk * 4 + r;
                int n   = row & 63;
                if (n < N_) {
                    int btc = p * 2 + (row >> 6);   // chunk-local
                    seqc[(size_t)btc * NG_ + n * 64 + co] =
                        f2bf(gelu_exact(acc2[i][j][r] + bias));
                }
            }
        }
    }
}

// ---------------------------------------------------------------------------
// bf16 MFMA GEMM: C = A(Mc x K) @ W(1024 x K)^T + bias_a + bias_b
// ---------------------------------------------------------------------------
__global__ __launch_bounds__(256) void gemm_mfma_kernel(
    const unsigned short* __restrict__ A, const unsigned short* __restrict__ W,
    const float* __restrict__ bias_a, const float* __restrict__ bias_b,
    float* __restrict__ Cout, int K, int m_base, int Mtot)
{
    __shared__ unsigned short As[128 * 32];
    __shared__ unsigned short Bs[128 * 32];

    const int tid = threadIdx.x;
    const int w   = tid >> 6;
    const int l   = tid & 63;
    const int wr  = w >> 1, wc = w & 1;
    const int lr  = l & 15, lk = l >> 4;

    const int m0 = blockIdx.x * 128;
    const int n0 = blockIdx.y * 128;

    f32x4 acc[4][4];
    #pragma unroll
    for (int i = 0; i < 4; ++i)
        #pragma unroll
        for (int j = 0; j < 4; ++j) acc[i][j] = (f32x4){0.f, 0.f, 0.f, 0.f};

    const int row_a0 = tid >> 2;
    const int cb     = (tid & 3) * 8;
    const unsigned short* aptr0 = A + (size_t)(m0 + row_a0) * K + cb;
    const unsigned short* aptr1 = A + (size_t)(m0 + row_a0 + 64) * K + cb;
    const unsigned short* bptr0 = W + (size_t)(n0 + row_a0) * K + cb;
    const unsigned short* bptr1 = W + (size_t)(n0 + row_a0 + 64) * K + cb;
    unsigned short* lA0 = &As[w * 512];
    unsigned short* lA1 = &As[2048 + w * 512];
    unsigned short* lB0 = &Bs[w * 512];
    unsigned short* lB1 = &Bs[2048 + w * 512];

    for (int k0 = 0; k0 < K; k0 += 32) {
        gload_lds16(aptr0 + k0, lA0);
        gload_lds16(aptr1 + k0, lA1);
        gload_lds16(bptr0 + k0, lB0);
        gload_lds16(bptr1 + k0, lB1);
        __syncthreads();

        bf16x8 af[4], bfr[4];
        #pragma unroll
        for (int i = 0; i < 4; ++i)
            af[i] = *reinterpret_cast<const bf16x8*>(&As[(wr * 64 + i * 16 + lr) * 32 + lk * 8]);
        #pragma unroll
        for (int j = 0; j < 4; ++j)
            bfr[j] = *reinterpret_cast<const bf16x8*>(&Bs[(wc * 64 + j * 16 + lr) * 32 + lk * 8]);
        #pragma unroll
        for (int i = 0; i < 4; ++i)
            #pragma unroll
            for (int j = 0; j < 4; ++j)
                acc[i][j] = __builtin_amdgcn_mfma_f32_16x16x32_bf16(af[i], bfr[j], acc[i][j], 0, 0, 0);
        __syncthreads();
    }

    #pragma unroll
    for (int i = 0; i < 4; ++i) {
        #pragma unroll
        for (int j = 0; j < 4; ++j) {
            int n = n0 + wc * 64 + j * 16 + lr;
            float ba = bias_a[n] + bias_b[n];
            int d = n >> 9, g = n & 511;
            #pragma unroll
            for (int r = 0; r < 4; ++r) {
                int m = m_base + m0 + wr * 64 + i * 16 + lk * 4 + r;
                Cout[((size_t)d * Mtot + m) * 512 + g] = acc[i][j][r] + ba;
            }
        }
    }
}

// ---------------------------------------------------------------------------
// MFMA-batched BiLSTM recurrence (FROZEN — r15 final: pipelined + fast
// transcendentals; ties the best scalar variant at ~286us; per-step floor
// ~2700 cyc is structural across all tested recurrence structures).
// ---------------------------------------------------------------------------
#define LSTM_STEP(S, PUSE)                                                          \
    {                                                                               \
        const int t_ = d ? (T_ - 1 - (S)) : (S);                                    \
        const char* hb_ = (const char*)&hbuf[cur][0];                               \
        const int rowb_ = lr * 256;                                                 \
        const int xo_   = (lr & 7) << 4;                                            \
        bf16x8 a0 = *reinterpret_cast<const bf16x8*>(hb_ + rowb_ + ((0 * 64 + lk * 16) ^ xo_)); \
        bf16x8 a1 = *reinterpret_cast<const bf16x8*>(hb_ + rowb_ + ((1 * 64 + lk * 16) ^ xo_)); \
        bf16x8 a2 = *reinterpret_cast<const bf16x8*>(hb_ + rowb_ + ((2 * 64 + lk * 16) ^ xo_)); \
        bf16x8 a3 = *reinterpret_cast<const bf16x8*>(hb_ + rowb_ + ((3 * 64 + lk * 16) ^ xo_)); \
        f32x4 acc_[4];                                                              \
        _Pragma("unroll")                                                           \
        for (int g_ = 0; g_ < 4; ++g_) acc_[g_] = PUSE[g_];                         \
        if ((S) + 2 < T_) {                                                         \
            int tn_ = d ? (T_ - 3 - (S)) : ((S) + 2);                               \
            _Pragma("unroll")                                                       \
            for (int g_ = 0; g_ < 4; ++g_)                                          \
                _Pragma("unroll")                                                   \
                for (int r_ = 0; r_ < 4; ++r_)                                      \
                    PUSE[g_][r_] = pb[((size_t)(lk * 4 + r_) * T_ + tn_) * 512 + g_ * 128]; \
        }                                                                           \
        _Pragma("unroll")                                                           \
        for (int g_ = 0; g_ < 4; ++g_) {                                            \
            acc_[g_] = __builtin_amdgcn_mfma_f32_16x16x32_bf16(a0, bw[g_][0], acc_[g_], 0, 0, 0); \
            acc_[g_] = __builtin_amdgcn_mfma_f32_16x16x32_bf16(a1, bw[g_][1], acc_[g_], 0, 0, 0); \
            acc_[g_] = __builtin_amdgcn_mfma_f32_16x16x32_bf16(a2, bw[g_][2], acc_[g_], 0, 0, 0); \
            acc_[g_] = __builtin_amdgcn_mfma_f32_16x16x32_bf16(a3, bw[g_][3], acc_[g_], 0, 0, 0); \
        }                                                                           \
        char* hn_ = (char*)&hbuf[cur ^ 1][0];                                       \
        _Pragma("unroll")                                                           \
        for (int r_ = 0; r_ < 4; ++r_) {                                            \
            float gi_ = acc_[0][r_], gf_ = acc_[1][r_];                             \
            float gv_ = acc_[2][r_], go_ = acc_[3][r_];                             \
            cst[r_] = fsig(gf_) * cst[r_] + fsig(gi_) * ftanh(gv_);                 \
            float h_ = fsig(go_) * ftanh(cst[r_]);                                  \
            int m_ = lk * 4 + r_;                                                   \
            *(unsigned short*)(hn_ + m_ * 256 + hswz(m_, unit * 2)) = f2bf(h_);     \
            store_h(&hout[((size_t)(bg * 16 + m_) * T_ + t_) * 256 + d * 128 + unit], h_); \
        }                                                                           \
        asm volatile("s_waitcnt lgkmcnt(0)" ::: "memory");                          \
        __builtin_amdgcn_s_barrier();                                               \
        __builtin_amdgcn_sched_barrier(0);                                          \
        cur ^= 1;                                                                   \
    }

template <typename OT>
__global__ __launch_bounds__(512) void lstm_kernel(
    const float* __restrict__ pre,           // [d][b][t][512]
    const unsigned short* __restrict__ Whb,  // [2][512][128] bf16
    OT* __restrict__ hout)                   // [b][t][256]
{
    const int d   = blockIdx.x >> 2;
    const int bg  = blockIdx.x & 3;
    const int tid = threadIdx.x;
    const int w   = tid >> 6;
    const int l   = tid & 63;
    const int lr  = l & 15;
    const int lk  = l >> 4;
    const int unit = w * 16 + lr;

    bf16x8 bw[4][4];
    #pragma unroll
    for (int g = 0; g < 4; ++g)
        #pragma unroll
        for (int kt = 0; kt < 4; ++kt)
            bw[g][kt] = *reinterpret_cast<const bf16x8*>(
                Whb + ((size_t)d * 512 + g * 128 + unit) * 128 + kt * 32 + lk * 8);

    __shared__ unsigned short hbuf[2][16 * 128];
    for (int i = tid; i < 1024; i += 512)
        reinterpret_cast<unsigned int*>(&hbuf[0][0])[i] = 0u;

    float cst[4] = {0.f, 0.f, 0.f, 0.f};

    const float* pb = pre + ((size_t)(d * B_ + bg * 16) * T_) * 512 + unit;

    f32x4 pE[4], pO[4];
    {
        int t0 = d ? (T_ - 1) : 0;
        int t1 = d ? (T_ - 2) : 1;
        #pragma unroll
        for (int g = 0; g < 4; ++g)
            #pragma unroll
            for (int r = 0; r < 4; ++r) {
                pE[g][r] = pb[((size_t)(lk * 4 + r) * T_ + t0) * 512 + g * 128];
                pO[g][r] = pb[((size_t)(lk * 4 + r) * T_ + t1) * 512 + g * 128];
            }
    }
    __syncthreads();

    int cur = 0;
    for (int s = 0; s < T_; s += 2) {
        LSTM_STEP(s,     pE);
        LSTM_STEP(s + 1, pO);
    }
}

// ---------------------------------------------------------------------------
// attention scores: block per (b, 32-t tile). Rows staged in LDS once.
// ---------------------------------------------------------------------------
__global__ __launch_bounds__(256) void attn_scores_kernel(
    const float* __restrict__ l1, const float* __restrict__ Wa1,
    const float* __restrict__ ba1, const float* __restrict__ Wa2,
    const float* __restrict__ ba2, float* __restrict__ scores)
{
    const int b   = blockIdx.x;
    const int t0  = blockIdx.y * 32;
    const int tid = threadIdx.x;
    const int j   = tid & 63, kq = tid >> 6;

    float w[64];
    const float* wsrc = Wa1 + j * 256 + kq * 64;
    #pragma unroll
    for (int k = 0; k < 64; ++k) w[k] = wsrc[k];

    __shared__ __align__(16) float rows[32 * 256];
    __shared__ float part[256];

    const float4* src = reinterpret_cast<const float4*>(
        l1 + (size_t)b * T_ * 256 + (size_t)t0 * 256);
    float4* dstv = reinterpret_cast<float4*>(rows);
    #pragma unroll
    for (int q = 0; q < 8; ++q) dstv[q * 256 + tid] = src[q * 256 + tid];

    float wa2 = (tid < 64) ? Wa2[tid] : 0.f;
    float bj  = (tid < 64) ? ba1[tid] : 0.f;
    float bb2 = ba2[0];
    __syncthreads();

    for (int tl = 0; tl < 32; ++tl) {
        const float* row = &rows[tl * 256 + kq * 64];
        float acc = 0.f;
        #pragma unroll
        for (int k4 = 0; k4 < 16; ++k4) {
            float4 hv = *reinterpret_cast<const float4*>(&row[k4 * 4]);
            acc += w[k4 * 4 + 0] * hv.x + w[k4 * 4 + 1] * hv.y
                 + w[k4 * 4 + 2] * hv.z + w[k4 * 4 + 3] * hv.w;
        }
        part[tid] = acc;
        __syncthreads();
        if (tid < 64) {
            float dj = part[tid] + part[tid + 64] + part[tid + 128] + part[tid + 192];
            float sv = tanhf(dj + bj) * wa2;
            #pragma unroll
            for (int off = 32; off > 0; off >>= 1) sv += __shfl_xor(sv, off);
            if (tid == 0) scores[b * T_ + t0 + tl] = sv + bb2;
        }
        __syncthreads();
    }
}

// ---------------------------------------------------------------------------
// softmax + context + classifier head: block per b.
// ---------------------------------------------------------------------------
__global__ __launch_bounds__(256) void attn_head_kernel(
    const float* __restrict__ l1, const float* __restrict__ scores,
    const float* __restrict__ Wc1, const float* __restrict__ bc1,
    const float* __restrict__ Wc2, const float* __restrict__ bc2,
    float* __restrict__ out)
{
    const int b   = blockIdx.x;
    const int tid = threadIdx.x;
    __shared__ float wsl[256];
    __shared__ float red[8];
    __shared__ float ctx[256];
    __shared__ float hid[128];
    __shared__ float wc1s[128 * 65];

    float v = scores[b * T_ + tid];
    float mx = v;
    #pragma unroll
    for (int off = 32; off > 0; off >>= 1) mx = fmaxf(mx, __shfl_xor(mx, off));
    if ((tid & 63) == 0) red[tid >> 6] = mx;
    __syncthreads();
    mx = fmaxf(fmaxf(red[0], red[1]), fmaxf(red[2], red[3]));
    float e = expf(v - mx);
    float s = e;
    #pragma unroll
    for (int off = 32; off > 0; off >>= 1) s += __shfl_xor(s, off);
    if ((tid & 63) == 0) red[4 + (tid >> 6)] = s;
    __syncthreads();
    float denom = red[4] + red[5] + red[6] + red[7];
    wsl[tid] = e / denom;
    __syncthreads();

    float acc = 0.f;
    const float* lb = l1 + (size_t)b * T_ * 256 + tid;
    #pragma unroll 4
    for (int t = 0; t < T_; ++t) acc += lb[(size_t)t * 256] * wsl[t];
    ctx[tid] = acc;
    __syncthreads();

    float hacc = (tid < 128) ? bc1[tid] : 0.f;
    for (int kb = 0; kb < 4; ++kb) {
        for (int i = tid; i < 128 * 64; i += 256) {
            int jj = i >> 6, kk = i & 63;
            wc1s[jj * 65 + kk] = Wc1[jj * 256 + kb * 64 + kk];
        }
        __syncthreads();
        if (tid < 128) {
            #pragma unroll
            for (int kk = 0; kk < 64; ++kk)
                hacc += ctx[kb * 64 + kk] * wc1s[tid * 65 + kk];
        }
        __syncthreads();
    }
    if (tid < 128) hid[tid] = fmaxf(hacc, 0.f);
    __syncthreads();

    if (tid < NC_) {
        float a = bc2[tid];
        #pragma unroll
        for (int k = 0; k < 128; ++k) a += hid[k] * Wc2[tid * 128 + k];
        out[b * NC_ + tid] = a;
    }
}

// ---------------------------------------------------------------------------
extern "C" void kernel_launch(void* const* d_in, const int* in_sizes, int n_in,
                              void* d_out, int out_size, void* d_ws, size_t ws_size,
                              hipStream_t stream)
{
    const float* x    = (const float*)d_in[0];
    const float* adj  = (const float*)d_in[1];
    const float* Wg1  = (const float*)d_in[2];
    const float* bg1  = (const float*)d_in[3];
    const float* Wg2  = (const float*)d_in[4];
    const float* bg2  = (const float*)d_in[5];
    const float* Wih0 = (const float*)d_in[6];
    const float* Whh0 = (const float*)d_in[7];
    const float* bih0 = (const float*)d_in[8];
    const float* bhh0 = (const float*)d_in[9];
    const float* Wih1 = (const float*)d_in[10];
    const float* Whh1 = (const float*)d_in[11];
    const float* bih1 = (const float*)d_in[12];
    const float* bhh1 = (const float*)d_in[13];
    const float* Wa1  = (const float*)d_in[14];
    const float* ba1  = (const float*)d_in[15];
    const float* Wa2  = (const float*)d_in[16];
    const float* ba2  = (const float*)d_in[17];
    const float* Wc1  = (const float*)d_in[18];
    const float* bc1  = (const float*)d_in[19];
    const float* Wc2  = (const float*)d_in[20];
    const float* bc2  = (const float*)d_in[21];

    char* ws = (char*)d_ws;
    // Workspace (bytes). Peak 156,946,432 < 160,432,128 proven by round-1 pass.
    // (H1W region no longer used — GCN is fused.)
    unsigned short* seqb = (unsigned short*)(ws);
    unsigned short* l0b  = (unsigned short*)(ws);
    float*          l1f  = (float*)(ws + 8388608);
    float*          scr  = (float*)(ws + 25165824);
    unsigned short* adjb = (unsigned short*)(ws + 80777216);
    unsigned short* w2b  = (unsigned short*)(ws + 80785408);
    float*          pre  = (float*)(ws + 80793600);
    unsigned short* W0b  = (unsigned short*)(ws + 147902464);
    unsigned short* W1b  = (unsigned short*)(ws + 155897856);
    unsigned short* W0hb = (unsigned short*)(ws + 156422144);
    unsigned short* W1hb = (unsigned short*)(ws + 156684288);

    const int n0e = in_sizes[6];    // 2*512*3904
    const int n1e = in_sizes[10];   // 2*512*256
    const int h0e = in_sizes[7];    // 2*512*128
    const int h1e = in_sizes[11];   // 2*512*128
    cvt_bf16_kernel<<<(n0e / 4 + 255) / 256, 256, 0, stream>>>(Wih0, W0b, n0e / 4);
    cvt_bf16_kernel<<<(n1e / 4 + 255) / 256, 256, 0, stream>>>(Wih1, W1b, n1e / 4);
    cvt_bf16_kernel<<<(h0e / 4 + 255) / 256, 256, 0, stream>>>(Whh0, W0hb, h0e / 4);
    cvt_bf16_kernel<<<(h1e / 4 + 255) / 256, 256, 0, stream>>>(Whh1, W1hb, h1e / 4);
    cvt_adj_kernel<<<16, 256, 0, stream>>>(adj, adjb);
    cvt_w2_kernel <<<16, 256, 0, stream>>>(Wg2, w2b);

    for (int ch = 0; ch < 2; ++ch) {
        int m_base = ch * CHUNK_M;
        gcn_fused_kernel<<<CHUNK_M / 2, 256, 0, stream>>>(
            x, adj, Wg1, bg1, adjb, w2b, bg2, seqb, m_base);
        gemm_mfma_kernel<<<dim3(CHUNK_M / 128, 8), 256, 0, stream>>>(
            seqb, W0b, bih0, bhh0, pre, NG_, m_base, M_TOT);
    }
    lstm_kernel<<<8, 512, 0, stream>>>(pre, W0hb, l0b);
    gemm_mfma_kernel<<<dim3(M_TOT / 128, 8), 256, 0, stream>>>(
        l0b, W1b, bih1, bhh1, pre, 256, 0, M_TOT);
    lstm_kernel<<<8, 512, 0, stream>>>(pre, W1hb, l1f);
    attn_scores_kernel<<<dim3(B_, 8), 256, 0, stream>>>(l1f, Wa1, ba1, Wa2, ba2, scr);
    attn_head_kernel<<<B_, 256, 0, stream>>>(l1f, scr, Wc1, bc1, Wc2, bc2, (float*)d_out);
}

// Round 19
// 1017.895 us; speedup vs baseline: 1.7164x; 1.0008x over previous
//
#include <hip/hip_runtime.h>
#include <math.h>

#define B_    64
#define T_    256
#define N_    61
#define FIN_  3
#define GH_   64
#define LH_   128
#define NC_   10
#define NG_   3904      /* N_*GH_ */
#define M_TOT 16384     /* B_*T_  */
#define CHUNK_M 8192

typedef __attribute__((ext_vector_type(8))) short bf16x8;
typedef __attribute__((ext_vector_type(4))) float f32x4;

__device__ __forceinline__ float gelu_exact(float x) {
    return 0.5f * x * (1.0f + erff(x * 0.70710678118654752f));
}
__device__ __forceinline__ float sigmoidf_(float x) {
    return 1.0f / (1.0f + expf(-x));
}
// fast HW transcendentals (LSTM gates only): v_exp_f32 + v_rcp_f32, ~1 ulp.
__device__ __forceinline__ float fsig(float x) {
    return __builtin_amdgcn_rcpf(1.f + __expf(-x));
}
__device__ __forceinline__ float ftanh(float x) {
    return 2.f * __builtin_amdgcn_rcpf(1.f + __expf(-2.f * x)) - 1.f;
}
__device__ __forceinline__ unsigned short f2bf(float f) {
    unsigned int u = __float_as_uint(f);
    u = (u + 0x7FFFu + ((u >> 16) & 1u)) >> 16;
    return (unsigned short)u;
}
__device__ __forceinline__ void store_h(float* p, float v) { *p = v; }
__device__ __forceinline__ void store_h(unsigned short* p, float v) { *p = f2bf(v); }

__device__ __forceinline__ void gload_lds16(const void* g, void* l) {
    __builtin_amdgcn_global_load_lds(
        (const __attribute__((address_space(1))) unsigned int*)g,
        (__attribute__((address_space(3))) unsigned int*)l,
        16, 0, 0);
}

// Shared 64-elem-row swizzle: XOR k with (row&3)*16. Used identically by every
// writer (global pre-swizzle / LDS write) and reader — both-sides-or-neither.
__device__ __forceinline__ int swz(int row, int k) { return k ^ ((row & 3) << 4); }

// byte-level row swizzle for 256B bf16 rows (T2): same map on write and read.
__device__ __forceinline__ int hswz(int row, int byteoff) { return byteoff ^ ((row & 7) << 4); }

// ---------------------------------------------------------------------------
// fp32 -> bf16 weight conversion (4 elems/thread). n4 = ELEMENT count / 4.
// (r18 lesson: the merged cvt_all kernel failed correctness twice despite
//  passing audit — reverted to these six proven launches for good.)
// ---------------------------------------------------------------------------
__global__ __launch_bounds__(256) void cvt_bf16_kernel(
    const float* __restrict__ in, unsigned short* __restrict__ out, int n4)
{
    int i = blockIdx.x * 256 + threadIdx.x;
    if (i < n4) {
        float4 v = reinterpret_cast<const float4*>(in)[i];
        ushort4 o;
        o.x = f2bf(v.x); o.y = f2bf(v.y); o.z = f2bf(v.z); o.w = f2bf(v.w);
        reinterpret_cast<ushort4*>(out)[i] = o;
    }
}

// adj (61x61 fp32) -> adjb (64x64 bf16, zero-padded, pre-swizzled). grid 16.
__global__ __launch_bounds__(256) void cvt_adj_kernel(
    const float* __restrict__ adj, unsigned short* __restrict__ adjb)
{
    int i = blockIdx.x * 256 + threadIdx.x;
    if (i < 4096) {
        int n = i >> 6, m = i & 63;
        unsigned short v = (n < N_ && m < N_) ? f2bf(adj[n * N_ + m]) : (unsigned short)0;
        adjb[n * 64 + swz(n, m)] = v;
    }
}

// W2 (64x64 fp32) -> w2b (64x64 bf16, pre-swizzled). grid 16.
__global__ __launch_bounds__(256) void cvt_w2_kernel(
    const float* __restrict__ W2, unsigned short* __restrict__ w2b)
{
    int i = blockIdx.x * 256 + threadIdx.x;
    if (i < 4096) {
        int c = i >> 6, f = i & 63;
        w2b[c * 64 + swz(c, f)] = f2bf(W2[c * 64 + f]);
    }
}

// ---------------------------------------------------------------------------
// FUSED GCN: one kernel per chunk (grid = CHUNK_M/2, block = 2 consecutive bt).
// ---------------------------------------------------------------------------
__global__ __launch_bounds__(256) void gcn_fused_kernel(
    const float* __restrict__ x, const float* __restrict__ adj,
    const float* __restrict__ W1, const float* __restrict__ b1,
    const unsigned short* __restrict__ adjb,   // [64][64] pre-swizzled bf16
    const unsigned short* __restrict__ w2b,    // [64][64] pre-swizzled bf16
    const float* __restrict__ b2,
    unsigned short* __restrict__ seqc,         // chunk-local [CHUNK_M][3904]
    int m_base)
{
    __shared__ __align__(16) char ldsbuf[53376];
    float*          adjs  = (float*)(ldsbuf);                    // phases A-B (61x65 f32)
    unsigned short* T     = (unsigned short*)(ldsbuf);           // phases D-E (union)
    unsigned short* b1t   = (unsigned short*)(ldsbuf + 16384);   // 128x64 bf16
    unsigned short* adjbs = (unsigned short*)(ldsbuf + 32768);   // 8KB
    unsigned short* w2bs  = (unsigned short*)(ldsbuf + 40960);   // 8KB
    float*          xs2   = (float*)(ldsbuf + 49152);            // 2x184
    float*          axs2  = (float*)(ldsbuf + 50624);            // 2x184
    float*          w1s   = (float*)(ldsbuf + 52096);            // 192
    float*          b1s   = (float*)(ldsbuf + 52864);            // 64
    float*          b2s   = (float*)(ldsbuf + 53120);            // 64

    const int tid = threadIdx.x;
    const int w   = tid >> 6;
    const int l   = tid & 63;
    const int lr  = l & 15, lk = l >> 4;
    const int p   = blockIdx.x;               // bt pair within chunk
    const int bt0 = m_base + p * 2;           // global bt of first

    // ---- A: staging
    #pragma unroll
    for (int q = 0; q < 2; ++q)
        gload_lds16(adjb + q * 2048 + w * 512 + l * 8, adjbs + q * 2048 + w * 512);
    #pragma unroll
    for (int q = 0; q < 2; ++q)
        gload_lds16(w2b + q * 2048 + w * 512 + l * 8, w2bs + q * 2048 + w * 512);
    for (int i = tid; i < N_ * N_; i += 256) {
        int n = i / 61, m = i - n * 61;
        adjs[n * 65 + m] = adj[i];
    }
    for (int i = tid; i < 2 * 183; i += 256) {
        int btl = i / 183, r = i - btl * 183;
        xs2[btl * 184 + r] = x[(size_t)(bt0 + btl) * 183 + r];
    }
    if (tid < 192) w1s[tid] = W1[tid];
    if (tid < 64) { b1s[tid] = b1[tid]; b2s[tid] = b2[tid]; }
    for (int i = tid; i < 4096; i += 256)          // zero b1t (pads m=61..63)
        reinterpret_cast<unsigned int*>(b1t)[i] = 0u;
    __syncthreads();

    // ---- B: AX (2 x 61x3), fp32
    if (tid < 366) {
        int btl = tid / 183, idx = tid - btl * 183;
        int n = idx / 3, f = idx - n * 3;
        float acc = 0.f;
        for (int m = 0; m < N_; ++m) acc += adjs[n * 65 + m] * xs2[btl * 184 + m * 3 + f];
        axs2[btl * 184 + idx] = acc;
    }
    __syncthreads();

    // ---- C: H1 = gelu(AX @ W1^T + b1) -> b1t bf16, transposed + swizzled
    for (int u = 0; u < 31; ++u) {
        int idx = tid + u * 256;
        if (idx < 2 * N_ * GH_) {
            int btl = idx / NG_;
            int r   = idx - btl * NG_;
            int m = r >> 6, c = r & 63;
            float acc = b1s[c];
            acc += axs2[btl * 184 + m * 3 + 0] * w1s[c * 3 + 0];
            acc += axs2[btl * 184 + m * 3 + 1] * w1s[c * 3 + 1];
            acc += axs2[btl * 184 + m * 3 + 2] * w1s[c * 3 + 2];
            b1t[(btl * 64 + c) * 64 + swz(c, m)] = f2bf(gelu_exact(acc));
        }
    }
    __syncthreads();   // adjs dead from here; T (union) may be written

    // ---- D: stage1 MFMA: AH1[n][col], wave w owns cols w*32..w*32+31
    f32x4 acc1[4][2];
    #pragma unroll
    for (int i = 0; i < 4; ++i)
        #pragma unroll
        for (int j = 0; j < 2; ++j) acc1[i][j] = (f32x4){0.f, 0.f, 0.f, 0.f};

    #pragma unroll
    for (int kk = 0; kk < 2; ++kk) {
        const int kb = kk * 32 + lk * 8;
        bf16x8 af[4], bfr[2];
        #pragma unroll
        for (int i = 0; i < 4; ++i) {
            int rn = i * 16 + lr;
            af[i] = *reinterpret_cast<const bf16x8*>(&adjbs[rn * 64 + swz(rn, kb)]);
        }
        #pragma unroll
        for (int j = 0; j < 2; ++j) {
            int rb = w * 32 + j * 16 + lr;
            bfr[j] = *reinterpret_cast<const bf16x8*>(&b1t[rb * 64 + swz(rb, kb)]);
        }
        #pragma unroll
        for (int i = 0; i < 4; ++i)
            #pragma unroll
            for (int j = 0; j < 2; ++j)
                acc1[i][j] = __builtin_amdgcn_mfma_f32_16x16x32_bf16(af[i], bfr[j], acc1[i][j], 0, 0, 0);
    }

    // bounce: AH1[n][col] -> T[(col>>6)*64 + n][col&63], bf16, swizzled
    #pragma unroll
    for (int i = 0; i < 4; ++i) {
        #pragma unroll
        for (int j = 0; j < 2; ++j) {
            int col = w * 32 + j * 16 + lr;
            int c   = col & 63;
            int rbase = (col >> 6) * 64;
            #pragma unroll
            for (int r = 0; r < 4; ++r) {
                int n   = i * 16 + lk * 4 + r;
                int row = rbase + n;
                T[row * 64 + swz(row, c)] = f2bf(acc1[i][j][r]);
            }
        }
    }
    __syncthreads();

    // ---- E: stage2 MFMA: seq = gelu(T @ w2b^T + b2)
    f32x4 acc2[2][4];
    #pragma unroll
    for (int i = 0; i < 2; ++i)
        #pragma unroll
        for (int j = 0; j < 4; ++j) acc2[i][j] = (f32x4){0.f, 0.f, 0.f, 0.f};

    #pragma unroll
    for (int kk = 0; kk < 2; ++kk) {
        const int kb = kk * 32 + lk * 8;
        bf16x8 a2[2], bwv[4];
        #pragma unroll
        for (int i = 0; i < 2; ++i) {
            int r2 = w * 32 + i * 16 + lr;
            a2[i] = *reinterpret_cast<const bf16x8*>(&T[r2 * 64 + swz(r2, kb)]);
        }
        #pragma unroll
        for (int j = 0; j < 4; ++j) {
            int co = j * 16 + lr;
            bwv[j] = *reinterpret_cast<const bf16x8*>(&w2bs[co * 64 + swz(co, kb)]);
        }
        #pragma unroll
        for (int i = 0; i < 2; ++i)
            #pragma unroll
            for (int j = 0; j < 4; ++j)
                acc2[i][j] = __builtin_amdgcn_mfma_f32_16x16x32_bf16(a2[i], bwv[j], acc2[i][j], 0, 0, 0);
    }

    #pragma unroll
    for (int i = 0; i < 2; ++i) {
        #pragma unroll
        for (int j = 0; j < 4; ++j) {
            int co = j * 16 + lr;
            float bias = b2s[co];
            #pragma unroll
            for (int r = 0; r < 4; ++r) {
                int row = w * 32 + i * 16 + lk * 4 + r;
                int n   = row & 63;
                if (n < N_) {
                    int btc = p * 2 + (row >> 6);   // chunk-local
                    seqc[(size_t)btc * NG_ + n * 64 + co] =
                        f2bf(gelu_exact(acc2[i][j][r] + bias));
                }
            }
        }
    }
}

// ---------------------------------------------------------------------------
// bf16 MFMA GEMM (general K): C = A(Mc x K) @ W(1024 x K)^T + bias_a + bias_b
// PROVEN r6-r16. Used for BOTH gemm0 (K=3904) and gemm1 (K=256).
// ---------------------------------------------------------------------------
__global__ __launch_bounds__(256) void gemm_mfma_kernel(
    const unsigned short* __restrict__ A, const unsigned short* __restrict__ W,
    const float* __restrict__ bias_a, const float* __restrict__ bias_b,
    float* __restrict__ Cout, int K, int m_base, int Mtot)
{
    __shared__ unsigned short As[128 * 32];
    __shared__ unsigned short Bs[128 * 32];

    const int tid = threadIdx.x;
    const int w   = tid >> 6;
    const int l   = tid & 63;
    const int wr  = w >> 1, wc = w & 1;
    const int lr  = l & 15, lk = l >> 4;

    const int m0 = blockIdx.x * 128;
    const int n0 = blockIdx.y * 128;

    f32x4 acc[4][4];
    #pragma unroll
    for (int i = 0; i < 4; ++i)
        #pragma unroll
        for (int j = 0; j < 4; ++j) acc[i][j] = (f32x4){0.f, 0.f, 0.f, 0.f};

    const int row_a0 = tid >> 2;
    const int cb     = (tid & 3) * 8;
    const unsigned short* aptr0 = A + (size_t)(m0 + row_a0) * K + cb;
    const unsigned short* aptr1 = A + (size_t)(m0 + row_a0 + 64) * K + cb;
    const unsigned short* bptr0 = W + (size_t)(n0 + row_a0) * K + cb;
    const unsigned short* bptr1 = W + (size_t)(n0 + row_a0 + 64) * K + cb;
    unsigned short* lA0 = &As[w * 512];
    unsigned short* lA1 = &As[2048 + w * 512];
    unsigned short* lB0 = &Bs[w * 512];
    unsigned short* lB1 = &Bs[2048 + w * 512];

    for (int k0 = 0; k0 < K; k0 += 32) {
        gload_lds16(aptr0 + k0, lA0);
        gload_lds16(aptr1 + k0, lA1);
        gload_lds16(bptr0 + k0, lB0);
        gload_lds16(bptr1 + k0, lB1);
        __syncthreads();

        bf16x8 af[4], bfr[4];
        #pragma unroll
        for (int i = 0; i < 4; ++i)
            af[i] = *reinterpret_cast<const bf16x8*>(&As[(wr * 64 + i * 16 + lr) * 32 + lk * 8]);
        #pragma unroll
        for (int j = 0; j < 4; ++j)
            bfr[j] = *reinterpret_cast<const bf16x8*>(&Bs[(wc * 64 + j * 16 + lr) * 32 + lk * 8]);
        #pragma unroll
        for (int i = 0; i < 4; ++i)
            #pragma unroll
            for (int j = 0; j < 4; ++j)
                acc[i][j] = __builtin_amdgcn_mfma_f32_16x16x32_bf16(af[i], bfr[j], acc[i][j], 0, 0, 0);
        __syncthreads();
    }

    #pragma unroll
    for (int i = 0; i < 4; ++i) {
        #pragma unroll
        for (int j = 0; j < 4; ++j) {
            int n = n0 + wc * 64 + j * 16 + lr;
            float ba = bias_a[n] + bias_b[n];
            int d = n >> 9, g = n & 511;
            #pragma unroll
            for (int r = 0; r < 4; ++r) {
                int m = m_base + m0 + wr * 64 + i * 16 + lk * 4 + r;
                Cout[((size_t)d * Mtot + m) * 512 + g] = acc[i][j][r] + ba;
            }
        }
    }
}

// ---------------------------------------------------------------------------
// MFMA-batched BiLSTM recurrence (FROZEN — r15 final).
// ---------------------------------------------------------------------------
#define LSTM_STEP(S, PUSE)                                                          \
    {                                                                               \
        const int t_ = d ? (T_ - 1 - (S)) : (S);                                    \
        const char* hb_ = (const char*)&hbuf[cur][0];                               \
        const int rowb_ = lr * 256;                                                 \
        const int xo_   = (lr & 7) << 4;                                            \
        bf16x8 a0 = *reinterpret_cast<const bf16x8*>(hb_ + rowb_ + ((0 * 64 + lk * 16) ^ xo_)); \
        bf16x8 a1 = *reinterpret_cast<const bf16x8*>(hb_ + rowb_ + ((1 * 64 + lk * 16) ^ xo_)); \
        bf16x8 a2 = *reinterpret_cast<const bf16x8*>(hb_ + rowb_ + ((2 * 64 + lk * 16) ^ xo_)); \
        bf16x8 a3 = *reinterpret_cast<const bf16x8*>(hb_ + rowb_ + ((3 * 64 + lk * 16) ^ xo_)); \
        f32x4 acc_[4];                                                              \
        _Pragma("unroll")                                                           \
        for (int g_ = 0; g_ < 4; ++g_) acc_[g_] = PUSE[g_];                         \
        if ((S) + 2 < T_) {                                                         \
            int tn_ = d ? (T_ - 3 - (S)) : ((S) + 2);                               \
            _Pragma("unroll")                                                       \
            for (int g_ = 0; g_ < 4; ++g_)                                          \
                _Pragma("unroll")                                                   \
                for (int r_ = 0; r_ < 4; ++r_)                                      \
                    PUSE[g_][r_] = pb[((size_t)(lk * 4 + r_) * T_ + tn_) * 512 + g_ * 128]; \
        }                                                                           \
        _Pragma("unroll")                                                           \
        for (int g_ = 0; g_ < 4; ++g_) {                                            \
            acc_[g_] = __builtin_amdgcn_mfma_f32_16x16x32_bf16(a0, bw[g_][0], acc_[g_], 0, 0, 0); \
            acc_[g_] = __builtin_amdgcn_mfma_f32_16x16x32_bf16(a1, bw[g_][1], acc_[g_], 0, 0, 0); \
            acc_[g_] = __builtin_amdgcn_mfma_f32_16x16x32_bf16(a2, bw[g_][2], acc_[g_], 0, 0, 0); \
            acc_[g_] = __builtin_amdgcn_mfma_f32_16x16x32_bf16(a3, bw[g_][3], acc_[g_], 0, 0, 0); \
        }                                                                           \
        char* hn_ = (char*)&hbuf[cur ^ 1][0];                                       \
        _Pragma("unroll")                                                           \
        for (int r_ = 0; r_ < 4; ++r_) {                                            \
            float gi_ = acc_[0][r_], gf_ = acc_[1][r_];                             \
            float gv_ = acc_[2][r_], go_ = acc_[3][r_];                             \
            cst[r_] = fsig(gf_) * cst[r_] + fsig(gi_) * ftanh(gv_);                 \
            float h_ = fsig(go_) * ftanh(cst[r_]);                                  \
            int m_ = lk * 4 + r_;                                                   \
            *(unsigned short*)(hn_ + m_ * 256 + hswz(m_, unit * 2)) = f2bf(h_);     \
            store_h(&hout[((size_t)(bg * 16 + m_) * T_ + t_) * 256 + d * 128 + unit], h_); \
        }                                                                           \
        asm volatile("s_waitcnt lgkmcnt(0)" ::: "memory");                          \
        __builtin_amdgcn_s_barrier();                                               \
        __builtin_amdgcn_sched_barrier(0);                                          \
        cur ^= 1;                                                                   \
    }

template <typename OT>
__global__ __launch_bounds__(512) void lstm_kernel(
    const float* __restrict__ pre,           // [d][b][t][512]
    const unsigned short* __restrict__ Whb,  // [2][512][128] bf16
    OT* __restrict__ hout)                   // [b][t][256]
{
    const int d   = blockIdx.x >> 2;
    const int bg  = blockIdx.x & 3;
    const int tid = threadIdx.x;
    const int w   = tid >> 6;
    const int l   = tid & 63;
    const int lr  = l & 15;
    const int lk  = l >> 4;
    const int unit = w * 16 + lr;

    bf16x8 bw[4][4];
    #pragma unroll
    for (int g = 0; g < 4; ++g)
        #pragma unroll
        for (int kt = 0; kt < 4; ++kt)
            bw[g][kt] = *reinterpret_cast<const bf16x8*>(
                Whb + ((size_t)d * 512 + g * 128 + unit) * 128 + kt * 32 + lk * 8);

    __shared__ unsigned short hbuf[2][16 * 128];
    for (int i = tid; i < 1024; i += 512)
        reinterpret_cast<unsigned int*>(&hbuf[0][0])[i] = 0u;

    float cst[4] = {0.f, 0.f, 0.f, 0.f};

    const float* pb = pre + ((size_t)(d * B_ + bg * 16) * T_) * 512 + unit;

    f32x4 pE[4], pO[4];
    {
        int t0 = d ? (T_ - 1) : 0;
        int t1 = d ? (T_ - 2) : 1;
        #pragma unroll
        for (int g = 0; g < 4; ++g)
            #pragma unroll
            for (int r = 0; r < 4; ++r) {
                pE[g][r] = pb[((size_t)(lk * 4 + r) * T_ + t0) * 512 + g * 128];
                pO[g][r] = pb[((size_t)(lk * 4 + r) * T_ + t1) * 512 + g * 128];
            }
    }
    __syncthreads();

    int cur = 0;
    for (int s = 0; s < T_; s += 2) {
        LSTM_STEP(s,     pE);
        LSTM_STEP(s + 1, pO);
    }
}

// ---------------------------------------------------------------------------
// attention scores: block per (b, 32-t tile). Rows staged in LDS once.
// ---------------------------------------------------------------------------
__global__ __launch_bounds__(256) void attn_scores_kernel(
    const float* __restrict__ l1, const float* __restrict__ Wa1,
    const float* __restrict__ ba1, const float* __restrict__ Wa2,
    const float* __restrict__ ba2, float* __restrict__ scores)
{
    const int b   = blockIdx.x;
    const int t0  = blockIdx.y * 32;
    const int tid = threadIdx.x;
    const int j   = tid & 63, kq = tid >> 6;

    float w[64];
    const float* wsrc = Wa1 + j * 256 + kq * 64;
    #pragma unroll
    for (int k = 0; k < 64; ++k) w[k] = wsrc[k];

    __shared__ __align__(16) float rows[32 * 256];
    __shared__ float part[256];

    const float4* src = reinterpret_cast<const float4*>(
        l1 + (size_t)b * T_ * 256 + (size_t)t0 * 256);
    float4* dstv = reinterpret_cast<float4*>(rows);
    #pragma unroll
    for (int q = 0; q < 8; ++q) dstv[q * 256 + tid] = src[q * 256 + tid];

    float wa2 = (tid < 64) ? Wa2[tid] : 0.f;
    float bj  = (tid < 64) ? ba1[tid] : 0.f;
    float bb2 = ba2[0];
    __syncthreads();

    for (int tl = 0; tl < 32; ++tl) {
        const float* row = &rows[tl * 256 + kq * 64];
        float acc = 0.f;
        #pragma unroll
        for (int k4 = 0; k4 < 16; ++k4) {
            float4 hv = *reinterpret_cast<const float4*>(&row[k4 * 4]);
            acc += w[k4 * 4 + 0] * hv.x + w[k4 * 4 + 1] * hv.y
                 + w[k4 * 4 + 2] * hv.z + w[k4 * 4 + 3] * hv.w;
        }
        part[tid] = acc;
        __syncthreads();
        if (tid < 64) {
            float dj = part[tid] + part[tid + 64] + part[tid + 128] + part[tid + 192];
            float sv = tanhf(dj + bj) * wa2;
            #pragma unroll
            for (int off = 32; off > 0; off >>= 1) sv += __shfl_xor(sv, off);
            if (tid == 0) scores[b * T_ + t0 + tl] = sv + bb2;
        }
        __syncthreads();
    }
}

// ---------------------------------------------------------------------------
// softmax + context + classifier head: block per b.
// ---------------------------------------------------------------------------
__global__ __launch_bounds__(256) void attn_head_kernel(
    const float* __restrict__ l1, const float* __restrict__ scores,
    const float* __restrict__ Wc1, const float* __restrict__ bc1,
    const float* __restrict__ Wc2, const float* __restrict__ bc2,
    float* __restrict__ out)
{
    const int b   = blockIdx.x;
    const int tid = threadIdx.x;
    __shared__ float wsl[256];
    __shared__ float red[8];
    __shared__ float ctx[256];
    __shared__ float hid[128];
    __shared__ float wc1s[128 * 65];

    float v = scores[b * T_ + tid];
    float mx = v;
    #pragma unroll
    for (int off = 32; off > 0; off >>= 1) mx = fmaxf(mx, __shfl_xor(mx, off));
    if ((tid & 63) == 0) red[tid >> 6] = mx;
    __syncthreads();
    mx = fmaxf(fmaxf(red[0], red[1]), fmaxf(red[2], red[3]));
    float e = expf(v - mx);
    float s = e;
    #pragma unroll
    for (int off = 32; off > 0; off >>= 1) s += __shfl_xor(s, off);
    if ((tid & 63) == 0) red[4 + (tid >> 6)] = s;
    __syncthreads();
    float denom = red[4] + red[5] + red[6] + red[7];
    wsl[tid] = e / denom;
    __syncthreads();

    float acc = 0.f;
    const float* lb = l1 + (size_t)b * T_ * 256 + tid;
    #pragma unroll 4
    for (int t = 0; t < T_; ++t) acc += lb[(size_t)t * 256] * wsl[t];
    ctx[tid] = acc;
    __syncthreads();

    float hacc = (tid < 128) ? bc1[tid] : 0.f;
    for (int kb = 0; kb < 4; ++kb) {
        for (int i = tid; i < 128 * 64; i += 256) {
            int jj = i >> 6, kk = i & 63;
            wc1s[jj * 65 + kk] = Wc1[jj * 256 + kb * 64 + kk];
        }
        __syncthreads();
        if (tid < 128) {
            #pragma unroll
            for (int kk = 0; kk < 64; ++kk)
                hacc += ctx[kb * 64 + kk] * wc1s[tid * 65 + kk];
        }
        __syncthreads();
    }
    if (tid < 128) hid[tid] = fmaxf(hacc, 0.f);
    __syncthreads();

    if (tid < NC_) {
        float a = bc2[tid];
        #pragma unroll
        for (int k = 0; k < 128; ++k) a += hid[k] * Wc2[tid * 128 + k];
        out[b * NC_ + tid] = a;
    }
}

// ---------------------------------------------------------------------------
extern "C" void kernel_launch(void* const* d_in, const int* in_sizes, int n_in,
                              void* d_out, int out_size, void* d_ws, size_t ws_size,
                              hipStream_t stream)
{
    const float* x    = (const float*)d_in[0];
    const float* adj  = (const float*)d_in[1];
    const float* Wg1  = (const float*)d_in[2];
    const float* bg1  = (const float*)d_in[3];
    const float* Wg2  = (const float*)d_in[4];
    const float* bg2  = (const float*)d_in[5];
    const float* Wih0 = (const float*)d_in[6];
    const float* Whh0 = (const float*)d_in[7];
    const float* bih0 = (const float*)d_in[8];
    const float* bhh0 = (const float*)d_in[9];
    const float* Wih1 = (const float*)d_in[10];
    const float* Whh1 = (const float*)d_in[11];
    const float* bih1 = (const float*)d_in[12];
    const float* bhh1 = (const float*)d_in[13];
    const float* Wa1  = (const float*)d_in[14];
    const float* ba1  = (const float*)d_in[15];
    const float* Wa2  = (const float*)d_in[16];
    const float* ba2  = (const float*)d_in[17];
    const float* Wc1  = (const float*)d_in[18];
    const float* bc1  = (const float*)d_in[19];
    const float* Wc2  = (const float*)d_in[20];
    const float* bc2  = (const float*)d_in[21];

    char* ws = (char*)d_ws;
    // Workspace (bytes). Peak 156,946,432 < 160,432,128 proven by round-1 pass.
    unsigned short* seqb = (unsigned short*)(ws);
    unsigned short* l0b  = (unsigned short*)(ws);
    float*          l1f  = (float*)(ws + 8388608);
    float*          scr  = (float*)(ws + 25165824);
    unsigned short* adjb = (unsigned short*)(ws + 80777216);
    unsigned short* w2b  = (unsigned short*)(ws + 80785408);
    float*          pre  = (float*)(ws + 80793600);
    unsigned short* W0b  = (unsigned short*)(ws + 147902464);
    unsigned short* W1b  = (unsigned short*)(ws + 155897856);
    unsigned short* W0hb = (unsigned short*)(ws + 156422144);
    unsigned short* W1hb = (unsigned short*)(ws + 156684288);

    const int n0e = in_sizes[6];    // 2*512*3904
    const int n1e = in_sizes[10];   // 2*512*256
    const int h0e = in_sizes[7];    // 2*512*128
    const int h1e = in_sizes[11];   // 2*512*128
    cvt_bf16_kernel<<<(n0e / 4 + 255) / 256, 256, 0, stream>>>(Wih0, W0b, n0e / 4);
    cvt_bf16_kernel<<<(n1e / 4 + 255) / 256, 256, 0, stream>>>(Wih1, W1b, n1e / 4);
    cvt_bf16_kernel<<<(h0e / 4 + 255) / 256, 256, 0, stream>>>(Whh0, W0hb, h0e / 4);
    cvt_bf16_kernel<<<(h1e / 4 + 255) / 256, 256, 0, stream>>>(Whh1, W1hb, h1e / 4);
    cvt_adj_kernel<<<16, 256, 0, stream>>>(adj, adjb);
    cvt_w2_kernel <<<16, 256, 0, stream>>>(Wg2, w2b);

    for (int ch = 0; ch < 2; ++ch) {
        int m_base = ch * CHUNK_M;
        gcn_fused_kernel<<<CHUNK_M / 2, 256, 0, stream>>>(
            x, adj, Wg1, bg1, adjb, w2b, bg2, seqb, m_base);
        gemm_mfma_kernel<<<dim3(CHUNK_M / 128, 8), 256, 0, stream>>>(
            seqb, W0b, bih0, bhh0, pre, NG_, m_base, M_TOT);
    }
    lstm_kernel<<<8, 512, 0, stream>>>(pre, W0hb, l0b);
    gemm_mfma_kernel<<<dim3(M_TOT / 128, 8), 256, 0, stream>>>(
        l0b, W1b, bih1, bhh1, pre, 256, 0, M_TOT);
    lstm_kernel<<<8, 512, 0, stream>>>(pre, W1hb, l1f);
    attn_scores_kernel<<<dim3(B_, 8), 256, 0, stream>>>(l1f, Wa1, ba1, Wa2, ba2, scr);
    attn_head_kernel<<<B_, 256, 0, stream>>>(l1f, scr, Wc1, bc1, Wc2, bc2, (float*)d_out);
}